// Round 8
// baseline (223.414 us; speedup 1.0000x reference)
//
#include <hip/hip_runtime.h>
#include <cstdint>
#include <cstddef>

// Fused transformer block: out = LN(FFN(LN(attn(x)+x)) + LN(attn(x)+x))
// Z=64, N=2048, D=64, DFF=32, causal, single head.
// proj: QKV via MFMA (+ Q pre-scaled, kpm pre-scaled, packed FFN weights).
// fused: split-kv flash attention (no-max base-2 softmax, additive merge)
//        + in-register LN/FFN/LN epilogue. Every wave = 33/32 kv-iterations.

#define ZB   64
#define NCTX 2048
#define DH   64
#define DFF  32
// base-2 softmax: score*SM_SCALE*log2(e); mask -1e9 pre-scale -> NEGS2 in log2 domain
#define SC2   0.18033688011112042f
#define NEGS2 (-1.8033688e8f)

typedef float f32x4  __attribute__((ext_vector_type(4)));
typedef float f32x16 __attribute__((ext_vector_type(16)));
typedef __bf16 bf16x8 __attribute__((ext_vector_type(8)));
typedef unsigned int u32x4 __attribute__((ext_vector_type(4)));

#define MFMA32(a, b, c) __builtin_amdgcn_mfma_f32_32x32x16_bf16((a), (b), (c), 0, 0, 0)

static __device__ __forceinline__ unsigned cvtpk_bf16(float a, float b) {
  unsigned r;
  asm("v_cvt_pk_bf16_f32 %0, %1, %2" : "=v"(r) : "v"(a), "v"(b));
  return r;
}
static __device__ __forceinline__ void plswap32(unsigned &a, unsigned &b) {
  asm volatile("v_permlane32_swap_b32 %0, %1" : "+v"(a), "+v"(b));
}
static __device__ __forceinline__ float exp2a(float x) {
  float r;
  asm("v_exp_f32 %0, %1" : "=v"(r) : "v"(x));
  return r;
}
static __device__ __forceinline__ float redsum32(float v) {
  return v + __shfl_xor(v, 32);   // lane^32; proven-correct path
}
// build a bf16x8 frag ordered {own-half, partner-half} from 8 f32 regs whose
// local row is rm = (r&3) + 8*(r>>2) + 4*hi (the 32x32 C-layout pattern)
static __device__ __forceinline__ bf16x8 pack_frag(
    float v0, float v1, float v2, float v3,
    float v4, float v5, float v6, float v7) {
  unsigned A0 = cvtpk_bf16(v0, v1), A1 = cvtpk_bf16(v2, v3);
  unsigned B0 = cvtpk_bf16(v4, v5), B1 = cvtpk_bf16(v6, v7);
  plswap32(A0, B0); plswap32(A1, B1);
  u32x4 u = {A0, A1, B0, B1};
  return __builtin_bit_cast(bf16x8, u);
}

// ---------------------------------------------------------------------------
// Kernel 1: QKV projection via MFMA (grid 1024 x 256, wave = 32-token tile).
// Q pre-scaled by SC2; kpmS = kpm*SC2; block 0 wave 0 packs w1/w2 into
// MFMA-frag layout for the fused epilogue's coalesced 16B frag loads.
// (unchanged from round 7 — proven)
// ---------------------------------------------------------------------------
__global__ __launch_bounds__(256) void proj_kernel(
    const float* __restrict__ x, const float* __restrict__ wq,
    const float* __restrict__ wk, const float* __restrict__ wv,
    const float* __restrict__ w1, const float* __restrict__ w2,
    const float* __restrict__ kpm,
    __bf16* __restrict__ Qb, __bf16* __restrict__ Kb, __bf16* __restrict__ Vt,
    float* __restrict__ kpmS, __bf16* __restrict__ w1p, __bf16* __restrict__ w2p)
{
  const int wid = threadIdx.x >> 6;
  const int l   = threadIdx.x & 63;
  const int q5  = l & 31, hi = l >> 5;
  const int tile = blockIdx.x * 4 + wid;        // 4096 tiles of 32 tokens
  const int b   = tile >> 6;                    // 64 tiles per batch
  const int n0  = (tile & 63) << 5;
  const int n   = n0 + q5;                      // this lane's token

  if (blockIdx.x == 0 && wid == 0) {
    #pragma unroll
    for (int kk = 0; kk < 4; ++kk)
      #pragma unroll
      for (int i = 0; i < 8; ++i)
        w1p[(kk * 64 + l) * 8 + i] = (__bf16)w1[(16 * kk + 8 * hi + i) * DFF + q5];
    #pragma unroll
    for (int dt = 0; dt < 2; ++dt)
      #pragma unroll
      for (int kk2 = 0; kk2 < 2; ++kk2)
        #pragma unroll
        for (int i = 0; i < 8; ++i)
          w2p[((dt * 2 + kk2) * 64 + l) * 8 + i] =
              (__bf16)w2[(16 * kk2 + 8 * hi + i) * DH + 32 * dt + q5];
  }
  if (hi == 0) kpmS[b * NCTX + n] = kpm[b * NCTX + n] * SC2;

  const float* xr = x + ((size_t)(b * NCTX + n)) * DH + 8 * hi;
  bf16x8 xb[4];
  #pragma unroll
  for (int kk = 0; kk < 4; ++kk) {
    const f32x4 a = *(const f32x4*)(xr + 16 * kk);
    const f32x4 c = *(const f32x4*)(xr + 16 * kk + 4);
    u32x4 u = {cvtpk_bf16(a[0], a[1]), cvtpk_bf16(a[2], a[3]),
               cvtpk_bf16(c[0], c[1]), cvtpk_bf16(c[2], c[3])};
    xb[kk] = __builtin_bit_cast(bf16x8, u);
  }

  const size_t rowb = ((size_t)(b * NCTX + n)) * DH;

  #pragma unroll
  for (int m = 0; m < 3; ++m) {
    const float* w = (m == 0) ? wq : (m == 1) ? wk : wv;

    f32x16 c0, c1;
    #pragma unroll
    for (int r = 0; r < 16; ++r) { c0[r] = 0.f; c1[r] = 0.f; }

    #pragma unroll
    for (int kk = 0; kk < 4; ++kk) {
      const float* wp = w + (size_t)(16 * kk + 8 * hi) * DH + q5;
      float f0[8], f1[8];
      #pragma unroll
      for (int i = 0; i < 8; ++i) { f0[i] = wp[i * DH]; f1[i] = wp[i * DH + 32]; }
      u32x4 ua = {cvtpk_bf16(f0[0], f0[1]), cvtpk_bf16(f0[2], f0[3]),
                  cvtpk_bf16(f0[4], f0[5]), cvtpk_bf16(f0[6], f0[7])};
      u32x4 ub = {cvtpk_bf16(f1[0], f1[1]), cvtpk_bf16(f1[2], f1[3]),
                  cvtpk_bf16(f1[4], f1[5]), cvtpk_bf16(f1[6], f1[7])};
      c0 = MFMA32(__builtin_bit_cast(bf16x8, ua), xb[kk], c0);
      c1 = MFMA32(__builtin_bit_cast(bf16x8, ub), xb[kk], c1);
    }

    if (m == 0) {
      #pragma unroll
      for (int r = 0; r < 16; ++r) { c0[r] *= SC2; c1[r] *= SC2; }
    }

    if (m < 2) {
      __bf16* dst = ((m == 0) ? Qb : Kb) + rowb + 32 * hi;
      #pragma unroll
      for (int g = 0; g < 4; ++g) {
        unsigned A0 = cvtpk_bf16(c0[4 * g],     c0[4 * g + 1]);
        unsigned A1 = cvtpk_bf16(c0[4 * g + 2], c0[4 * g + 3]);
        unsigned B0 = cvtpk_bf16(c1[4 * g],     c1[4 * g + 1]);
        unsigned B1 = cvtpk_bf16(c1[4 * g + 2], c1[4 * g + 3]);
        plswap32(A0, B0); plswap32(A1, B1);
        u32x4 u = {A0, A1, B0, B1};
        *(u32x4*)(dst + 8 * g) = u;
      }
    } else {
      __bf16* vb = Vt + (size_t)b * DH * NCTX + n;
      #pragma unroll
      for (int r = 0; r < 16; ++r) {
        const int d = (r & 3) + 8 * (r >> 2) + 4 * hi;
        vb[(size_t)d * NCTX]        = (__bf16)c0[r];
        vb[(size_t)(d + 32) * NCTX] = (__bf16)c1[r];
      }
    }
  }
}

// ---------------------------------------------------------------------------
// attn phase: q-tile t, kv tiles [j0, j1). No-max base-2 softmax (m=0):
// p = exp2(s + kpmS [+ NEGS2 diag mask]); masked -> exactly 0. Accumulates
// acc (unnormalized PV) and lsq (per-lane own-half denominator partial).
// K regs double-buffered (2x unrolled, no copies); V + kpm issued at
// iteration top so their latency hides under QK MFMAs + exp.
// ---------------------------------------------------------------------------
static __device__ __forceinline__ void attn_phase(
    const __bf16* __restrict__ qrow,   // Qb + (b*NCTX + t*32 + q5)*DH + 8hi
    const __bf16* __restrict__ kbase,  // Kb + (b*NCTX + q5)*DH + 8hi
    const __bf16* __restrict__ vbase,  // Vt + (b*DH + q5)*NCTX + 8hi
    const float*  __restrict__ kpb,    // kpmS + b*NCTX
    int T, int j0, int j1, int q5, int hi,
    f32x16& acc0, f32x16& acc1, float& lsq)
{
  if (j0 >= j1) return;

  const bf16x8 qf0 = *(const bf16x8*)(qrow);
  const bf16x8 qf1 = *(const bf16x8*)(qrow + 16);
  const bf16x8 qf2 = *(const bf16x8*)(qrow + 32);
  const bf16x8 qf3 = *(const bf16x8*)(qrow + 48);

  f32x16 z16;
  #pragma unroll
  for (int r = 0; r < 16; ++r) z16[r] = 0.f;

  bf16x8 kA0, kA1, kA2, kA3, kB0, kB1, kB2, kB3;
  {
    const __bf16* kp = kbase + (size_t)j0 * 32 * DH;
    kA0 = *(const bf16x8*)(kp);      kA1 = *(const bf16x8*)(kp + 16);
    kA2 = *(const bf16x8*)(kp + 32); kA3 = *(const bf16x8*)(kp + 48);
  }
  int j = j0;

#define ATTN_ITER(KC0, KC1, KC2, KC3, KN0, KN1, KN2, KN3)                   \
  {                                                                         \
    const bool last = (j + 1 >= j1);                                        \
    const bool dg = last && (j1 == T);                                      \
    const __bf16* vp = vbase + (size_t)j * 32;                              \
    const bf16x8 vf0 = *(const bf16x8*)(vp);                                \
    const bf16x8 vf1 = *(const bf16x8*)(vp + 16);                           \
    const bf16x8 vf2 = *(const bf16x8*)(vp + (size_t)32 * NCTX);            \
    const bf16x8 vf3 = *(const bf16x8*)(vp + (size_t)32 * NCTX + 16);       \
    const float* kp2 = kpb + j * 32 + 4 * hi;                               \
    f32x4 km[4];                                                            \
    km[0] = *(const f32x4*)(kp2);      km[1] = *(const f32x4*)(kp2 + 8);    \
    km[2] = *(const f32x4*)(kp2 + 16); km[3] = *(const f32x4*)(kp2 + 24);   \
    if (!last) {                                                            \
      const __bf16* kp = kbase + (size_t)(j + 1) * 32 * DH;                 \
      KN0 = *(const bf16x8*)(kp);      KN1 = *(const bf16x8*)(kp + 16);     \
      KN2 = *(const bf16x8*)(kp + 32); KN3 = *(const bf16x8*)(kp + 48);     \
    }                                                                       \
    __builtin_amdgcn_s_setprio(1);                                          \
    f32x16 s = MFMA32(KC0, qf0, z16);                                       \
    s = MFMA32(KC1, qf1, s);                                                \
    s = MFMA32(KC2, qf2, s);                                                \
    s = MFMA32(KC3, qf3, s);                                                \
    __builtin_amdgcn_s_setprio(0);                                          \
    float p[16];                                                            \
    if (dg) {                                                               \
      _Pragma("unroll")                                                     \
      for (int r = 0; r < 16; ++r) {                                        \
        const int rm = (r & 3) + 8 * (r >> 2) + 4 * hi;                     \
        const float tv = s[r] + km[r >> 2][r & 3] + ((rm > q5) ? NEGS2 : 0.f); \
        p[r] = exp2a(tv);                                                   \
      }                                                                     \
    } else {                                                                \
      _Pragma("unroll")                                                     \
      for (int r = 0; r < 16; ++r) p[r] = exp2a(s[r] + km[r >> 2][r & 3]);  \
    }                                                                       \
    lsq += ((p[0] + p[1]) + (p[2] + p[3])) + ((p[4] + p[5]) + (p[6] + p[7]))  \
         + ((p[8] + p[9]) + (p[10] + p[11])) + ((p[12] + p[13]) + (p[14] + p[15])); \
    const bf16x8 pf0 = pack_frag(p[0], p[1], p[2],  p[3],  p[4],  p[5],  p[6],  p[7]);  \
    const bf16x8 pf1 = pack_frag(p[8], p[9], p[10], p[11], p[12], p[13], p[14], p[15]); \
    __builtin_amdgcn_s_setprio(1);                                          \
    acc0 = MFMA32(vf0, pf0, acc0);                                          \
    acc0 = MFMA32(vf1, pf1, acc0);                                          \
    acc1 = MFMA32(vf2, pf0, acc1);                                          \
    acc1 = MFMA32(vf3, pf1, acc1);                                          \
    __builtin_amdgcn_s_setprio(0);                                          \
  }

  for (;;) {
    ATTN_ITER(kA0, kA1, kA2, kA3, kB0, kB1, kB2, kB3);
    if (++j >= j1) break;
    ATTN_ITER(kB0, kB1, kB2, kB3, kA0, kA1, kA2, kA3);
    if (++j >= j1) break;
  }
#undef ATTN_ITER
}

// ---------------------------------------------------------------------------
// Kernel 2: fused split-kv attention + LN + FFN + LN.
// grid = Z*32 x 128 (2 waves). Block tp owns q-tiles t1=tp, t2=63-tp.
// wave0: [tile t1, kv 0..h1) -> dump | [tile t2, kv 0..h2) -> keep
// wave1: [tile t2, kv h2..T2) -> dump | [tile t1, kv h1..T1) -> keep
// Every wave = 33/32 iterations (tail-free). Merge = plain add (no-max
// softmax partials are shift-free). One __syncthreads. Epilogue per wave
// on its kept tile: y=LN(O/ls + x); h=relu(w1p.y); ff=w2p.h; out=LN(ff+y).
// ---------------------------------------------------------------------------
__global__ __launch_bounds__(128, 4) void fused_kernel(
    const __bf16* __restrict__ Qb, const __bf16* __restrict__ Kb,
    const __bf16* __restrict__ Vt, const float* __restrict__ kpmS,
    const float* __restrict__ x,
    const __bf16* __restrict__ w1p, const __bf16* __restrict__ w2p,
    float* __restrict__ out)
{
  const int bid = (blockIdx.x & 7) * 256 + (blockIdx.x >> 3);  // XCD chunking
  const int b   = bid >> 5;
  const int tp  = bid & 31;
  const int wv  = threadIdx.x >> 6;
  const int l   = threadIdx.x & 63;
  const int q5  = l & 31;
  const int hi  = l >> 5;

  const int t1 = tp, t2 = 63 - tp;
  const int T1 = t1 + 1, T2 = t2 + 1;
  const int h1 = (T1 + 1) >> 1, h2 = (T2 + 1) >> 1;

  __shared__ float part[2][64][36];   // [wave][lane][acc0|acc1|ls] (stride 36)

  const __bf16* kbase = Kb + ((size_t)b * NCTX + q5) * DH + hi * 8;
  const __bf16* vbase = Vt + ((size_t)(b * DH + q5)) * NCTX + hi * 8;
  const float*  kpb   = kpmS + b * NCTX;
  const __bf16* qbb   = Qb + ((size_t)b * NCTX + q5) * DH + hi * 8;

  f32x16 acc0, acc1;
  float lsq;

  // ---- phase A (dumped to LDS) ----
  #pragma unroll
  for (int r = 0; r < 16; ++r) { acc0[r] = 0.f; acc1[r] = 0.f; }
  lsq = 0.f;
  if (wv == 0) attn_phase(qbb + (size_t)t1 * 32 * DH, kbase, vbase, kpb,
                          T1, 0, h1, q5, hi, acc0, acc1, lsq);
  else         attn_phase(qbb + (size_t)t2 * 32 * DH, kbase, vbase, kpb,
                          T2, h2, T2, q5, hi, acc0, acc1, lsq);
  {
    float* ps = &part[wv][l][0];
    #pragma unroll
    for (int g = 0; g < 4; ++g) {
      f32x4 t0, t1v;
      #pragma unroll
      for (int jj = 0; jj < 4; ++jj) { t0[jj] = acc0[4 * g + jj]; t1v[jj] = acc1[4 * g + jj]; }
      *(f32x4*)(ps + 4 * g)      = t0;
      *(f32x4*)(ps + 16 + 4 * g) = t1v;
    }
    ps[32] = lsq;
  }

  // ---- phase B (kept in regs) ----
  #pragma unroll
  for (int r = 0; r < 16; ++r) { acc0[r] = 0.f; acc1[r] = 0.f; }
  lsq = 0.f;
  const int tB = wv ? t1 : t2;
  if (wv == 0) attn_phase(qbb + (size_t)t2 * 32 * DH, kbase, vbase, kpb,
                          T2, 0, h2, q5, hi, acc0, acc1, lsq);
  else         attn_phase(qbb + (size_t)t1 * 32 * DH, kbase, vbase, kpb,
                          T1, h1, T1, q5, hi, acc0, acc1, lsq);

  __syncthreads();

  // ---- merge partner's partial (plain add: no-max softmax) ----
  {
    const float* po = &part[wv ^ 1][l][0];
    #pragma unroll
    for (int g = 0; g < 4; ++g) {
      const f32x4 t0 = *(const f32x4*)(po + 4 * g);
      const f32x4 t1v = *(const f32x4*)(po + 16 + 4 * g);
      #pragma unroll
      for (int jj = 0; jj < 4; ++jj) { acc0[4 * g + jj] += t0[jj]; acc1[4 * g + jj] += t1v[jj]; }
    }
    lsq += po[32];
  }

  // ---- fused epilogue: LN1 + FFN + LN2 on tile tB ----
  const int n = tB * 32 + q5;
  const float invl = 1.f / redsum32(lsq);
  const float* xrow = x + ((size_t)(b * NCTX + n)) * DH;

  f32x16 z16;
  #pragma unroll
  for (int r = 0; r < 16; ++r) z16[r] = 0.f;

  float y0[16], y1[16];
  float s1 = 0.f, s2 = 0.f;
  #pragma unroll
  for (int g = 0; g < 4; ++g) {
    const f32x4 xv0 = *(const f32x4*)(xrow + 8 * g + 4 * hi);
    const f32x4 xv1 = *(const f32x4*)(xrow + 32 + 8 * g + 4 * hi);
    #pragma unroll
    for (int jj = 0; jj < 4; ++jj) {
      const float a0 = acc0[4 * g + jj] * invl + xv0[jj];
      const float a1 = acc1[4 * g + jj] * invl + xv1[jj];
      y0[4 * g + jj] = a0; y1[4 * g + jj] = a1;
      s1 += a0 + a1; s2 += a0 * a0 + a1 * a1;
    }
  }
  s1 = redsum32(s1);
  s2 = redsum32(s2);
  {
    const float mu   = s1 * (1.f / 64.f);
    const float var  = s2 * (1.f / 64.f) - mu * mu;
    const float rstd = rsqrtf(var + 1e-5f);
    #pragma unroll
    for (int r = 0; r < 16; ++r) {
      y0[r] = (y0[r] - mu) * rstd;
      y1[r] = (y1[r] - mu) * rstd;
    }
  }

  const bf16x8 yb0 = pack_frag(y0[0], y0[1], y0[2],  y0[3],  y0[4],  y0[5],  y0[6],  y0[7]);
  const bf16x8 yb1 = pack_frag(y0[8], y0[9], y0[10], y0[11], y0[12], y0[13], y0[14], y0[15]);
  const bf16x8 yb2 = pack_frag(y1[0], y1[1], y1[2],  y1[3],  y1[4],  y1[5],  y1[6],  y1[7]);
  const bf16x8 yb3 = pack_frag(y1[8], y1[9], y1[10], y1[11], y1[12], y1[13], y1[14], y1[15]);

  const __bf16* wp1 = w1p + (size_t)l * 8;
  f32x16 hc;
  hc = MFMA32(*(const bf16x8*)(wp1),              yb0, z16);
  hc = MFMA32(*(const bf16x8*)(wp1 + 64 * 8),     yb1, hc);
  hc = MFMA32(*(const bf16x8*)(wp1 + 2 * 64 * 8), yb2, hc);
  hc = MFMA32(*(const bf16x8*)(wp1 + 3 * 64 * 8), yb3, hc);
  float hv[16];
  #pragma unroll
  for (int r = 0; r < 16; ++r) hv[r] = fmaxf(hc[r], 0.f);

  const bf16x8 hb0 = pack_frag(hv[0], hv[1], hv[2],  hv[3],  hv[4],  hv[5],  hv[6],  hv[7]);
  const bf16x8 hb1 = pack_frag(hv[8], hv[9], hv[10], hv[11], hv[12], hv[13], hv[14], hv[15]);

  const __bf16* wp2 = w2p + (size_t)l * 8;
  f32x16 f20, f21;
  f20 = MFMA32(*(const bf16x8*)(wp2),              hb0, z16);
  f20 = MFMA32(*(const bf16x8*)(wp2 + 64 * 8),     hb1, f20);
  f21 = MFMA32(*(const bf16x8*)(wp2 + 2 * 64 * 8), hb0, z16);
  f21 = MFMA32(*(const bf16x8*)(wp2 + 3 * 64 * 8), hb1, f21);

  float v1 = 0.f, v2 = 0.f;
  float va0[16], va1[16];
  #pragma unroll
  for (int r = 0; r < 16; ++r) {
    va0[r] = f20[r] + y0[r];
    va1[r] = f21[r] + y1[r];
    v1 += va0[r] + va1[r];
    v2 += va0[r] * va0[r] + va1[r] * va1[r];
  }
  v1 = redsum32(v1);
  v2 = redsum32(v2);
  const float mu2   = v1 * (1.f / 64.f);
  const float var2  = v2 * (1.f / 64.f) - mu2 * mu2;
  const float rstd2 = rsqrtf(var2 + 1e-5f);

  float* op = out + ((size_t)(b * NCTX + n)) * DH + 4 * hi;
  #pragma unroll
  for (int g = 0; g < 4; ++g) {
    f32x4 st0, st1;
    #pragma unroll
    for (int jj = 0; jj < 4; ++jj) {
      st0[jj] = (va0[4 * g + jj] - mu2) * rstd2;
      st1[jj] = (va1[4 * g + jj] - mu2) * rstd2;
    }
    *(f32x4*)(op + 8 * g)      = st0;
    *(f32x4*)(op + 32 + 8 * g) = st1;
  }
}

// ---------------------------------------------------------------------------
extern "C" void kernel_launch(void* const* d_in, const int* in_sizes, int n_in,
                              void* d_out, int out_size, void* d_ws, size_t ws_size,
                              hipStream_t stream)
{
  const float* x   = (const float*)d_in[0];
  const float* wq  = (const float*)d_in[1];
  const float* wk  = (const float*)d_in[2];
  const float* wv  = (const float*)d_in[3];
  const float* w1  = (const float*)d_in[4];
  const float* w2  = (const float*)d_in[5];
  const float* kpm = (const float*)d_in[6];
  // d_in[7] = causal_mask: handled structurally (triu(k=1) == -1e9 additive)
  float* out = (float*)d_out;

  char* ws = (char*)d_ws;
  const size_t nelem = (size_t)ZB * NCTX * DH;     // 8388608
  __bf16* Qb   = (__bf16*)(ws);
  __bf16* Kb   = (__bf16*)(ws + nelem * 2);
  __bf16* Vt   = (__bf16*)(ws + nelem * 4);        // [Z][D][N]
  float*  kpmS = (float*)(ws + nelem * 6);         // ZB*NCTX f32
  __bf16* w1p  = (__bf16*)(ws + nelem * 6 + (size_t)ZB * NCTX * 4);
  __bf16* w2p  = w1p + 4 * 64 * 8;

  proj_kernel <<<1024, 256, 0, stream>>>(x, wq, wk, wv, w1, w2, kpm,
                                         Qb, Kb, Vt, kpmS, w1p, w2p);
  fused_kernel<<<ZB * 32, 128, 0, stream>>>(Qb, Kb, Vt, kpmS, x, w1p, w2p, out);
}

// Round 9
// 178.142 us; speedup vs baseline: 1.2541x; 1.2541x over previous
//
#include <hip/hip_runtime.h>
#include <cstdint>
#include <cstddef>

// Fused transformer block: out = LN(FFN(LN(attn(x)+x)) + LN(attn(x)+x))
// Z=64, N=2048, D=64, DFF=32, causal, single head.
// proj: QKV via MFMA (+ Q pre-scaled, kpm pre-scaled, packed FFN weights).
// fused: split-kv flash attention (no-max base-2 softmax, additive merge)
//        + in-register LN/FFN/LN epilogue. Every wave = 33/32 kv-iterations.
// R9: __launch_bounds__(128) — R8's (128,4) hint forced VGPR 128->64 and
//     spilled ~400MB/dispatch to scratch (FETCH 41->141MB, WRITE 33->329MB).

#define ZB   64
#define NCTX 2048
#define DH   64
#define DFF  32
// base-2 softmax: score*SM_SCALE*log2(e); mask -1e9 pre-scale -> NEGS2 in log2 domain
#define SC2   0.18033688011112042f
#define NEGS2 (-1.8033688e8f)

typedef float f32x4  __attribute__((ext_vector_type(4)));
typedef float f32x16 __attribute__((ext_vector_type(16)));
typedef __bf16 bf16x8 __attribute__((ext_vector_type(8)));
typedef unsigned int u32x4 __attribute__((ext_vector_type(4)));

#define MFMA32(a, b, c) __builtin_amdgcn_mfma_f32_32x32x16_bf16((a), (b), (c), 0, 0, 0)

static __device__ __forceinline__ unsigned cvtpk_bf16(float a, float b) {
  unsigned r;
  asm("v_cvt_pk_bf16_f32 %0, %1, %2" : "=v"(r) : "v"(a), "v"(b));
  return r;
}
static __device__ __forceinline__ void plswap32(unsigned &a, unsigned &b) {
  asm volatile("v_permlane32_swap_b32 %0, %1" : "+v"(a), "+v"(b));
}
static __device__ __forceinline__ float exp2a(float x) {
  float r;
  asm("v_exp_f32 %0, %1" : "=v"(r) : "v"(x));
  return r;
}
static __device__ __forceinline__ float redsum32(float v) {
  return v + __shfl_xor(v, 32);   // lane^32; proven-correct path
}
// build a bf16x8 frag ordered {own-half, partner-half} from 8 f32 regs whose
// local row is rm = (r&3) + 8*(r>>2) + 4*hi (the 32x32 C-layout pattern)
static __device__ __forceinline__ bf16x8 pack_frag(
    float v0, float v1, float v2, float v3,
    float v4, float v5, float v6, float v7) {
  unsigned A0 = cvtpk_bf16(v0, v1), A1 = cvtpk_bf16(v2, v3);
  unsigned B0 = cvtpk_bf16(v4, v5), B1 = cvtpk_bf16(v6, v7);
  plswap32(A0, B0); plswap32(A1, B1);
  u32x4 u = {A0, A1, B0, B1};
  return __builtin_bit_cast(bf16x8, u);
}

// ---------------------------------------------------------------------------
// Kernel 1: QKV projection via MFMA (grid 1024 x 256, wave = 32-token tile).
// Q pre-scaled by SC2; kpmS = kpm*SC2; block 0 wave 0 packs w1/w2 into
// MFMA-frag layout for the fused epilogue's coalesced 16B frag loads.
// (unchanged — proven)
// ---------------------------------------------------------------------------
__global__ __launch_bounds__(256) void proj_kernel(
    const float* __restrict__ x, const float* __restrict__ wq,
    const float* __restrict__ wk, const float* __restrict__ wv,
    const float* __restrict__ w1, const float* __restrict__ w2,
    const float* __restrict__ kpm,
    __bf16* __restrict__ Qb, __bf16* __restrict__ Kb, __bf16* __restrict__ Vt,
    float* __restrict__ kpmS, __bf16* __restrict__ w1p, __bf16* __restrict__ w2p)
{
  const int wid = threadIdx.x >> 6;
  const int l   = threadIdx.x & 63;
  const int q5  = l & 31, hi = l >> 5;
  const int tile = blockIdx.x * 4 + wid;        // 4096 tiles of 32 tokens
  const int b   = tile >> 6;                    // 64 tiles per batch
  const int n0  = (tile & 63) << 5;
  const int n   = n0 + q5;                      // this lane's token

  if (blockIdx.x == 0 && wid == 0) {
    #pragma unroll
    for (int kk = 0; kk < 4; ++kk)
      #pragma unroll
      for (int i = 0; i < 8; ++i)
        w1p[(kk * 64 + l) * 8 + i] = (__bf16)w1[(16 * kk + 8 * hi + i) * DFF + q5];
    #pragma unroll
    for (int dt = 0; dt < 2; ++dt)
      #pragma unroll
      for (int kk2 = 0; kk2 < 2; ++kk2)
        #pragma unroll
        for (int i = 0; i < 8; ++i)
          w2p[((dt * 2 + kk2) * 64 + l) * 8 + i] =
              (__bf16)w2[(16 * kk2 + 8 * hi + i) * DH + 32 * dt + q5];
  }
  if (hi == 0) kpmS[b * NCTX + n] = kpm[b * NCTX + n] * SC2;

  const float* xr = x + ((size_t)(b * NCTX + n)) * DH + 8 * hi;
  bf16x8 xb[4];
  #pragma unroll
  for (int kk = 0; kk < 4; ++kk) {
    const f32x4 a = *(const f32x4*)(xr + 16 * kk);
    const f32x4 c = *(const f32x4*)(xr + 16 * kk + 4);
    u32x4 u = {cvtpk_bf16(a[0], a[1]), cvtpk_bf16(a[2], a[3]),
               cvtpk_bf16(c[0], c[1]), cvtpk_bf16(c[2], c[3])};
    xb[kk] = __builtin_bit_cast(bf16x8, u);
  }

  const size_t rowb = ((size_t)(b * NCTX + n)) * DH;

  #pragma unroll
  for (int m = 0; m < 3; ++m) {
    const float* w = (m == 0) ? wq : (m == 1) ? wk : wv;

    f32x16 c0, c1;
    #pragma unroll
    for (int r = 0; r < 16; ++r) { c0[r] = 0.f; c1[r] = 0.f; }

    #pragma unroll
    for (int kk = 0; kk < 4; ++kk) {
      const float* wp = w + (size_t)(16 * kk + 8 * hi) * DH + q5;
      float f0[8], f1[8];
      #pragma unroll
      for (int i = 0; i < 8; ++i) { f0[i] = wp[i * DH]; f1[i] = wp[i * DH + 32]; }
      u32x4 ua = {cvtpk_bf16(f0[0], f0[1]), cvtpk_bf16(f0[2], f0[3]),
                  cvtpk_bf16(f0[4], f0[5]), cvtpk_bf16(f0[6], f0[7])};
      u32x4 ub = {cvtpk_bf16(f1[0], f1[1]), cvtpk_bf16(f1[2], f1[3]),
                  cvtpk_bf16(f1[4], f1[5]), cvtpk_bf16(f1[6], f1[7])};
      c0 = MFMA32(__builtin_bit_cast(bf16x8, ua), xb[kk], c0);
      c1 = MFMA32(__builtin_bit_cast(bf16x8, ub), xb[kk], c1);
    }

    if (m == 0) {
      #pragma unroll
      for (int r = 0; r < 16; ++r) { c0[r] *= SC2; c1[r] *= SC2; }
    }

    if (m < 2) {
      __bf16* dst = ((m == 0) ? Qb : Kb) + rowb + 32 * hi;
      #pragma unroll
      for (int g = 0; g < 4; ++g) {
        unsigned A0 = cvtpk_bf16(c0[4 * g],     c0[4 * g + 1]);
        unsigned A1 = cvtpk_bf16(c0[4 * g + 2], c0[4 * g + 3]);
        unsigned B0 = cvtpk_bf16(c1[4 * g],     c1[4 * g + 1]);
        unsigned B1 = cvtpk_bf16(c1[4 * g + 2], c1[4 * g + 3]);
        plswap32(A0, B0); plswap32(A1, B1);
        u32x4 u = {A0, A1, B0, B1};
        *(u32x4*)(dst + 8 * g) = u;
      }
    } else {
      __bf16* vb = Vt + (size_t)b * DH * NCTX + n;
      #pragma unroll
      for (int r = 0; r < 16; ++r) {
        const int d = (r & 3) + 8 * (r >> 2) + 4 * hi;
        vb[(size_t)d * NCTX]        = (__bf16)c0[r];
        vb[(size_t)(d + 32) * NCTX] = (__bf16)c1[r];
      }
    }
  }
}

// ---------------------------------------------------------------------------
// attn phase: q-tile t, kv tiles [j0, j1). No-max base-2 softmax (m=0):
// p = exp2(s + kpmS [+ NEGS2 diag mask]); masked -> exactly 0. Accumulates
// acc (unnormalized PV) and lsq (per-lane own-half denominator partial).
// K regs double-buffered (2x unrolled, no copies); V + kpm issued at
// iteration top so their latency hides under QK MFMAs + exp.
// ---------------------------------------------------------------------------
static __device__ __forceinline__ void attn_phase(
    const __bf16* __restrict__ qrow,   // Qb + (b*NCTX + t*32 + q5)*DH + 8hi
    const __bf16* __restrict__ kbase,  // Kb + (b*NCTX + q5)*DH + 8hi
    const __bf16* __restrict__ vbase,  // Vt + (b*DH + q5)*NCTX + 8hi
    const float*  __restrict__ kpb,    // kpmS + b*NCTX
    int T, int j0, int j1, int q5, int hi,
    f32x16& acc0, f32x16& acc1, float& lsq)
{
  if (j0 >= j1) return;

  const bf16x8 qf0 = *(const bf16x8*)(qrow);
  const bf16x8 qf1 = *(const bf16x8*)(qrow + 16);
  const bf16x8 qf2 = *(const bf16x8*)(qrow + 32);
  const bf16x8 qf3 = *(const bf16x8*)(qrow + 48);

  f32x16 z16;
  #pragma unroll
  for (int r = 0; r < 16; ++r) z16[r] = 0.f;

  bf16x8 kA0, kA1, kA2, kA3, kB0, kB1, kB2, kB3;
  {
    const __bf16* kp = kbase + (size_t)j0 * 32 * DH;
    kA0 = *(const bf16x8*)(kp);      kA1 = *(const bf16x8*)(kp + 16);
    kA2 = *(const bf16x8*)(kp + 32); kA3 = *(const bf16x8*)(kp + 48);
  }
  int j = j0;

#define ATTN_ITER(KC0, KC1, KC2, KC3, KN0, KN1, KN2, KN3)                   \
  {                                                                         \
    const bool last = (j + 1 >= j1);                                        \
    const bool dg = last && (j1 == T);                                      \
    const __bf16* vp = vbase + (size_t)j * 32;                              \
    const bf16x8 vf0 = *(const bf16x8*)(vp);                                \
    const bf16x8 vf1 = *(const bf16x8*)(vp + 16);                           \
    const bf16x8 vf2 = *(const bf16x8*)(vp + (size_t)32 * NCTX);            \
    const bf16x8 vf3 = *(const bf16x8*)(vp + (size_t)32 * NCTX + 16);       \
    const float* kp2 = kpb + j * 32 + 4 * hi;                               \
    f32x4 km[4];                                                            \
    km[0] = *(const f32x4*)(kp2);      km[1] = *(const f32x4*)(kp2 + 8);    \
    km[2] = *(const f32x4*)(kp2 + 16); km[3] = *(const f32x4*)(kp2 + 24);   \
    if (!last) {                                                            \
      const __bf16* kp = kbase + (size_t)(j + 1) * 32 * DH;                 \
      KN0 = *(const bf16x8*)(kp);      KN1 = *(const bf16x8*)(kp + 16);     \
      KN2 = *(const bf16x8*)(kp + 32); KN3 = *(const bf16x8*)(kp + 48);     \
    }                                                                       \
    __builtin_amdgcn_s_setprio(1);                                          \
    f32x16 s = MFMA32(KC0, qf0, z16);                                       \
    s = MFMA32(KC1, qf1, s);                                                \
    s = MFMA32(KC2, qf2, s);                                                \
    s = MFMA32(KC3, qf3, s);                                                \
    __builtin_amdgcn_s_setprio(0);                                          \
    float p[16];                                                            \
    if (dg) {                                                               \
      _Pragma("unroll")                                                     \
      for (int r = 0; r < 16; ++r) {                                        \
        const int rm = (r & 3) + 8 * (r >> 2) + 4 * hi;                     \
        const float tv = s[r] + km[r >> 2][r & 3] + ((rm > q5) ? NEGS2 : 0.f); \
        p[r] = exp2a(tv);                                                   \
      }                                                                     \
    } else {                                                                \
      _Pragma("unroll")                                                     \
      for (int r = 0; r < 16; ++r) p[r] = exp2a(s[r] + km[r >> 2][r & 3]);  \
    }                                                                       \
    lsq += ((p[0] + p[1]) + (p[2] + p[3])) + ((p[4] + p[5]) + (p[6] + p[7]))  \
         + ((p[8] + p[9]) + (p[10] + p[11])) + ((p[12] + p[13]) + (p[14] + p[15])); \
    const bf16x8 pf0 = pack_frag(p[0], p[1], p[2],  p[3],  p[4],  p[5],  p[6],  p[7]);  \
    const bf16x8 pf1 = pack_frag(p[8], p[9], p[10], p[11], p[12], p[13], p[14], p[15]); \
    __builtin_amdgcn_s_setprio(1);                                          \
    acc0 = MFMA32(vf0, pf0, acc0);                                          \
    acc0 = MFMA32(vf1, pf1, acc0);                                          \
    acc1 = MFMA32(vf2, pf0, acc1);                                          \
    acc1 = MFMA32(vf3, pf1, acc1);                                          \
    __builtin_amdgcn_s_setprio(0);                                          \
  }

  for (;;) {
    ATTN_ITER(kA0, kA1, kA2, kA3, kB0, kB1, kB2, kB3);
    if (++j >= j1) break;
    ATTN_ITER(kB0, kB1, kB2, kB3, kA0, kA1, kA2, kA3);
    if (++j >= j1) break;
  }
#undef ATTN_ITER
}

// ---------------------------------------------------------------------------
// Kernel 2: fused split-kv attention + LN + FFN + LN.
// grid = Z*32 x 128 (2 waves). Block tp owns q-tiles t1=tp, t2=63-tp.
// wave0: [tile t1, kv 0..h1) -> dump | [tile t2, kv 0..h2) -> keep
// wave1: [tile t2, kv h2..T2) -> dump | [tile t1, kv h1..T1) -> keep
// Every wave = 33/32 iterations (tail-free). Merge = plain add (no-max
// softmax partials are shift-free). One __syncthreads. Epilogue per wave
// on its kept tile: y=LN(O/ls + x); h=relu(w1p.y); ff=w2p.h; out=LN(ff+y).
// ---------------------------------------------------------------------------
__global__ __launch_bounds__(128) void fused_kernel(
    const __bf16* __restrict__ Qb, const __bf16* __restrict__ Kb,
    const __bf16* __restrict__ Vt, const float* __restrict__ kpmS,
    const float* __restrict__ x,
    const __bf16* __restrict__ w1p, const __bf16* __restrict__ w2p,
    float* __restrict__ out)
{
  const int bid = (blockIdx.x & 7) * 256 + (blockIdx.x >> 3);  // XCD chunking
  const int b   = bid >> 5;
  const int tp  = bid & 31;
  const int wv  = threadIdx.x >> 6;
  const int l   = threadIdx.x & 63;
  const int q5  = l & 31;
  const int hi  = l >> 5;

  const int t1 = tp, t2 = 63 - tp;
  const int T1 = t1 + 1, T2 = t2 + 1;
  const int h1 = (T1 + 1) >> 1, h2 = (T2 + 1) >> 1;

  __shared__ float part[2][64][36];   // [wave][lane][acc0|acc1|ls] (stride 36)

  const __bf16* kbase = Kb + ((size_t)b * NCTX + q5) * DH + hi * 8;
  const __bf16* vbase = Vt + ((size_t)(b * DH + q5)) * NCTX + hi * 8;
  const float*  kpb   = kpmS + b * NCTX;
  const __bf16* qbb   = Qb + ((size_t)b * NCTX + q5) * DH + hi * 8;

  f32x16 acc0, acc1;
  float lsq;

  // ---- phase A (dumped to LDS) ----
  #pragma unroll
  for (int r = 0; r < 16; ++r) { acc0[r] = 0.f; acc1[r] = 0.f; }
  lsq = 0.f;
  if (wv == 0) attn_phase(qbb + (size_t)t1 * 32 * DH, kbase, vbase, kpb,
                          T1, 0, h1, q5, hi, acc0, acc1, lsq);
  else         attn_phase(qbb + (size_t)t2 * 32 * DH, kbase, vbase, kpb,
                          T2, h2, T2, q5, hi, acc0, acc1, lsq);
  {
    float* ps = &part[wv][l][0];
    #pragma unroll
    for (int g = 0; g < 4; ++g) {
      f32x4 t0, t1v;
      #pragma unroll
      for (int jj = 0; jj < 4; ++jj) { t0[jj] = acc0[4 * g + jj]; t1v[jj] = acc1[4 * g + jj]; }
      *(f32x4*)(ps + 4 * g)      = t0;
      *(f32x4*)(ps + 16 + 4 * g) = t1v;
    }
    ps[32] = lsq;
  }

  // ---- phase B (kept in regs) ----
  #pragma unroll
  for (int r = 0; r < 16; ++r) { acc0[r] = 0.f; acc1[r] = 0.f; }
  lsq = 0.f;
  const int tB = wv ? t1 : t2;
  if (wv == 0) attn_phase(qbb + (size_t)t2 * 32 * DH, kbase, vbase, kpb,
                          T2, 0, h2, q5, hi, acc0, acc1, lsq);
  else         attn_phase(qbb + (size_t)t1 * 32 * DH, kbase, vbase, kpb,
                          T1, h1, T1, q5, hi, acc0, acc1, lsq);

  __syncthreads();

  // ---- merge partner's partial (plain add: no-max softmax) ----
  {
    const float* po = &part[wv ^ 1][l][0];
    #pragma unroll
    for (int g = 0; g < 4; ++g) {
      const f32x4 t0 = *(const f32x4*)(po + 4 * g);
      const f32x4 t1v = *(const f32x4*)(po + 16 + 4 * g);
      #pragma unroll
      for (int jj = 0; jj < 4; ++jj) { acc0[4 * g + jj] += t0[jj]; acc1[4 * g + jj] += t1v[jj]; }
    }
    lsq += po[32];
  }

  // ---- fused epilogue: LN1 + FFN + LN2 on tile tB ----
  const int n = tB * 32 + q5;
  const float invl = 1.f / redsum32(lsq);
  const float* xrow = x + ((size_t)(b * NCTX + n)) * DH;

  f32x16 z16;
  #pragma unroll
  for (int r = 0; r < 16; ++r) z16[r] = 0.f;

  float y0[16], y1[16];
  float s1 = 0.f, s2 = 0.f;
  #pragma unroll
  for (int g = 0; g < 4; ++g) {
    const f32x4 xv0 = *(const f32x4*)(xrow + 8 * g + 4 * hi);
    const f32x4 xv1 = *(const f32x4*)(xrow + 32 + 8 * g + 4 * hi);
    #pragma unroll
    for (int jj = 0; jj < 4; ++jj) {
      const float a0 = acc0[4 * g + jj] * invl + xv0[jj];
      const float a1 = acc1[4 * g + jj] * invl + xv1[jj];
      y0[4 * g + jj] = a0; y1[4 * g + jj] = a1;
      s1 += a0 + a1; s2 += a0 * a0 + a1 * a1;
    }
  }
  s1 = redsum32(s1);
  s2 = redsum32(s2);
  {
    const float mu   = s1 * (1.f / 64.f);
    const float var  = s2 * (1.f / 64.f) - mu * mu;
    const float rstd = rsqrtf(var + 1e-5f);
    #pragma unroll
    for (int r = 0; r < 16; ++r) {
      y0[r] = (y0[r] - mu) * rstd;
      y1[r] = (y1[r] - mu) * rstd;
    }
  }

  const bf16x8 yb0 = pack_frag(y0[0], y0[1], y0[2],  y0[3],  y0[4],  y0[5],  y0[6],  y0[7]);
  const bf16x8 yb1 = pack_frag(y0[8], y0[9], y0[10], y0[11], y0[12], y0[13], y0[14], y0[15]);
  const bf16x8 yb2 = pack_frag(y1[0], y1[1], y1[2],  y1[3],  y1[4],  y1[5],  y1[6],  y1[7]);
  const bf16x8 yb3 = pack_frag(y1[8], y1[9], y1[10], y1[11], y1[12], y1[13], y1[14], y1[15]);

  const __bf16* wp1 = w1p + (size_t)l * 8;
  f32x16 hc;
  hc = MFMA32(*(const bf16x8*)(wp1),              yb0, z16);
  hc = MFMA32(*(const bf16x8*)(wp1 + 64 * 8),     yb1, hc);
  hc = MFMA32(*(const bf16x8*)(wp1 + 2 * 64 * 8), yb2, hc);
  hc = MFMA32(*(const bf16x8*)(wp1 + 3 * 64 * 8), yb3, hc);
  float hv[16];
  #pragma unroll
  for (int r = 0; r < 16; ++r) hv[r] = fmaxf(hc[r], 0.f);

  const bf16x8 hb0 = pack_frag(hv[0], hv[1], hv[2],  hv[3],  hv[4],  hv[5],  hv[6],  hv[7]);
  const bf16x8 hb1 = pack_frag(hv[8], hv[9], hv[10], hv[11], hv[12], hv[13], hv[14], hv[15]);

  const __bf16* wp2 = w2p + (size_t)l * 8;
  f32x16 f20, f21;
  f20 = MFMA32(*(const bf16x8*)(wp2),              hb0, z16);
  f20 = MFMA32(*(const bf16x8*)(wp2 + 64 * 8),     hb1, f20);
  f21 = MFMA32(*(const bf16x8*)(wp2 + 2 * 64 * 8), hb0, z16);
  f21 = MFMA32(*(const bf16x8*)(wp2 + 3 * 64 * 8), hb1, f21);

  float v1 = 0.f, v2 = 0.f;
  float va0[16], va1[16];
  #pragma unroll
  for (int r = 0; r < 16; ++r) {
    va0[r] = f20[r] + y0[r];
    va1[r] = f21[r] + y1[r];
    v1 += va0[r] + va1[r];
    v2 += va0[r] * va0[r] + va1[r] * va1[r];
  }
  v1 = redsum32(v1);
  v2 = redsum32(v2);
  const float mu2   = v1 * (1.f / 64.f);
  const float var2  = v2 * (1.f / 64.f) - mu2 * mu2;
  const float rstd2 = rsqrtf(var2 + 1e-5f);

  float* op = out + ((size_t)(b * NCTX + n)) * DH + 4 * hi;
  #pragma unroll
  for (int g = 0; g < 4; ++g) {
    f32x4 st0, st1;
    #pragma unroll
    for (int jj = 0; jj < 4; ++jj) {
      st0[jj] = (va0[4 * g + jj] - mu2) * rstd2;
      st1[jj] = (va1[4 * g + jj] - mu2) * rstd2;
    }
    *(f32x4*)(op + 8 * g)      = st0;
    *(f32x4*)(op + 32 + 8 * g) = st1;
  }
}

// ---------------------------------------------------------------------------
extern "C" void kernel_launch(void* const* d_in, const int* in_sizes, int n_in,
                              void* d_out, int out_size, void* d_ws, size_t ws_size,
                              hipStream_t stream)
{
  const float* x   = (const float*)d_in[0];
  const float* wq  = (const float*)d_in[1];
  const float* wk  = (const float*)d_in[2];
  const float* wv  = (const float*)d_in[3];
  const float* w1  = (const float*)d_in[4];
  const float* w2  = (const float*)d_in[5];
  const float* kpm = (const float*)d_in[6];
  // d_in[7] = causal_mask: handled structurally (triu(k=1) == -1e9 additive)
  float* out = (float*)d_out;

  char* ws = (char*)d_ws;
  const size_t nelem = (size_t)ZB * NCTX * DH;     // 8388608
  __bf16* Qb   = (__bf16*)(ws);
  __bf16* Kb   = (__bf16*)(ws + nelem * 2);
  __bf16* Vt   = (__bf16*)(ws + nelem * 4);        // [Z][D][N]
  float*  kpmS = (float*)(ws + nelem * 6);         // ZB*NCTX f32
  __bf16* w1p  = (__bf16*)(ws + nelem * 6 + (size_t)ZB * NCTX * 4);
  __bf16* w2p  = w1p + 4 * 64 * 8;

  proj_kernel <<<1024, 256, 0, stream>>>(x, wq, wk, wv, w1, w2, kpm,
                                         Qb, Kb, Vt, kpmS, w1p, w2p);
  fused_kernel<<<ZB * 32, 128, 0, stream>>>(Qb, Kb, Vt, kpmS, x, w1p, w2p, out);
}

// Round 10
// 104.571 us; speedup vs baseline: 2.1365x; 1.7036x over previous
//
#include <hip/hip_runtime.h>
#include <cstdint>
#include <cstddef>

// Fused transformer block: out = LN(FFN(LN(attn(x)+x)) + LN(attn(x)+x))
// Z=64, N=2048, D=64, DFF=32, causal, single head.
// proj: QKV via MFMA -> FRAGMENT-PACKED layouts Qp/Kp/Vp[b][tile][frag][lane][8]
//       so every fused inner-loop load is a coalesced 16B/lane (R9 was a
//       128B/4KB-lane-stride gather = 32-64 cache lines per instruction).
// fused: split-kv flash attention (no-max base-2 softmax, additive merge)
//        + in-register LN/FFN/LN epilogue. Every wave = ~33 kv-iterations.

#define ZB   64
#define NCTX 2048
#define DH   64
#define DFF  32
// base-2 softmax: score*SM_SCALE*log2(e); mask -1e9 pre-scale -> NEGS2 in log2 domain
#define SC2   0.18033688011112042f
#define NEGS2 (-1.8033688e8f)

typedef float f32x4  __attribute__((ext_vector_type(4)));
typedef float f32x16 __attribute__((ext_vector_type(16)));
typedef __bf16 bf16x8 __attribute__((ext_vector_type(8)));
typedef unsigned int u32x4 __attribute__((ext_vector_type(4)));

#define MFMA32(a, b, c) __builtin_amdgcn_mfma_f32_32x32x16_bf16((a), (b), (c), 0, 0, 0)

static __device__ __forceinline__ unsigned cvtpk_bf16(float a, float b) {
  unsigned r;
  asm("v_cvt_pk_bf16_f32 %0, %1, %2" : "=v"(r) : "v"(a), "v"(b));
  return r;
}
static __device__ __forceinline__ void plswap32(unsigned &a, unsigned &b) {
  asm volatile("v_permlane32_swap_b32 %0, %1" : "+v"(a), "+v"(b));
}
static __device__ __forceinline__ float exp2a(float x) {
  float r;
  asm("v_exp_f32 %0, %1" : "=v"(r) : "v"(x));
  return r;
}
static __device__ __forceinline__ float redsum32(float v) {
  return v + __shfl_xor(v, 32);   // lane^32; proven-correct path
}
// build a bf16x8 frag ordered {own-half, partner-half} from 8 f32 regs whose
// local row is rm = (r&3) + 8*(r>>2) + 4*hi (the 32x32 C-layout pattern)
static __device__ __forceinline__ bf16x8 pack_frag(
    float v0, float v1, float v2, float v3,
    float v4, float v5, float v6, float v7) {
  unsigned A0 = cvtpk_bf16(v0, v1), A1 = cvtpk_bf16(v2, v3);
  unsigned B0 = cvtpk_bf16(v4, v5), B1 = cvtpk_bf16(v6, v7);
  plswap32(A0, B0); plswap32(A1, B1);
  u32x4 u = {A0, A1, B0, B1};
  return __builtin_bit_cast(bf16x8, u);
}

// ---------------------------------------------------------------------------
// Kernel 1: QKV projection via MFMA (grid 1024 x 256, wave = 32-token tile).
// Outputs in fragment-packed order (frag stride 512 elem, tile stride 2048):
//   Qp/Kp[b][tk][c][l][8]: lane l=(q5,hi') frag c holds Q[tok q5][16c+8hi'+i]
//   Vp[b][tk][f][l][8]: f=(db,kvh); lane l=(d5,hi) holds V[16kvh+8hi+i][d5+32db]
// Q pre-scaled by SC2; kpmS = kpm*SC2; block 0 wave 0 packs w1p/w2p.
// ---------------------------------------------------------------------------
__global__ __launch_bounds__(256) void proj_kernel(
    const float* __restrict__ x, const float* __restrict__ wq,
    const float* __restrict__ wk, const float* __restrict__ wv,
    const float* __restrict__ w1, const float* __restrict__ w2,
    const float* __restrict__ kpm,
    __bf16* __restrict__ Qp, __bf16* __restrict__ Kp, __bf16* __restrict__ Vp,
    float* __restrict__ kpmS, __bf16* __restrict__ w1p, __bf16* __restrict__ w2p)
{
  const int wid = threadIdx.x >> 6;
  const int l   = threadIdx.x & 63;
  const int q5  = l & 31, hi = l >> 5;
  const int tile = blockIdx.x * 4 + wid;        // 4096 tiles of 32 tokens
  const int b   = tile >> 6;                    // 64 tiles per batch
  const int tk  = tile & 63;                    // tile index within batch
  const int n   = (tk << 5) + q5;               // this lane's token

  __shared__ float vtile[4][32][67];            // [wave][token][d], 67: bank-clean

  if (blockIdx.x == 0 && wid == 0) {
    #pragma unroll
    for (int kk = 0; kk < 4; ++kk)
      #pragma unroll
      for (int i = 0; i < 8; ++i)
        w1p[(kk * 64 + l) * 8 + i] = (__bf16)w1[(16 * kk + 8 * hi + i) * DFF + q5];
    #pragma unroll
    for (int dt = 0; dt < 2; ++dt)
      #pragma unroll
      for (int kk2 = 0; kk2 < 2; ++kk2)
        #pragma unroll
        for (int i = 0; i < 8; ++i)
          w2p[((dt * 2 + kk2) * 64 + l) * 8 + i] =
              (__bf16)w2[(16 * kk2 + 8 * hi + i) * DH + 32 * dt + q5];
  }
  if (hi == 0) kpmS[b * NCTX + n] = kpm[b * NCTX + n] * SC2;

  const float* xr = x + ((size_t)(b * NCTX + n)) * DH + 8 * hi;
  bf16x8 xb[4];
  #pragma unroll
  for (int kk = 0; kk < 4; ++kk) {
    const f32x4 a = *(const f32x4*)(xr + 16 * kk);
    const f32x4 c = *(const f32x4*)(xr + 16 * kk + 4);
    u32x4 u = {cvtpk_bf16(a[0], a[1]), cvtpk_bf16(a[2], a[3]),
               cvtpk_bf16(c[0], c[1]), cvtpk_bf16(c[2], c[3])};
    xb[kk] = __builtin_bit_cast(bf16x8, u);
  }

  const size_t tbase = ((size_t)(b * 64 + tk)) * 2048;   // packed tile base

  #pragma unroll
  for (int m = 0; m < 3; ++m) {
    const float* w = (m == 0) ? wq : (m == 1) ? wk : wv;

    f32x16 c0, c1;
    #pragma unroll
    for (int r = 0; r < 16; ++r) { c0[r] = 0.f; c1[r] = 0.f; }

    #pragma unroll
    for (int kk = 0; kk < 4; ++kk) {
      const float* wp = w + (size_t)(16 * kk + 8 * hi) * DH + q5;
      float f0[8], f1[8];
      #pragma unroll
      for (int i = 0; i < 8; ++i) { f0[i] = wp[i * DH]; f1[i] = wp[i * DH + 32]; }
      u32x4 ua = {cvtpk_bf16(f0[0], f0[1]), cvtpk_bf16(f0[2], f0[3]),
                  cvtpk_bf16(f0[4], f0[5]), cvtpk_bf16(f0[6], f0[7])};
      u32x4 ub = {cvtpk_bf16(f1[0], f1[1]), cvtpk_bf16(f1[2], f1[3]),
                  cvtpk_bf16(f1[4], f1[5]), cvtpk_bf16(f1[6], f1[7])};
      c0 = MFMA32(__builtin_bit_cast(bf16x8, ua), xb[kk], c0);
      c1 = MFMA32(__builtin_bit_cast(bf16x8, ub), xb[kk], c1);
    }

    if (m == 0) {
      #pragma unroll
      for (int r = 0; r < 16; ++r) { c0[r] *= SC2; c1[r] *= SC2; }
    }

    if (m < 2) {
      // same verified pack as the old row-major store (content = token q5,
      // d-octet [32hi+8g, +8)); only the ADDRESS changes to packed order:
      // frag c = 2hi + (g>>1), slot = (g&1)*32 + q5.
      __bf16* dst = ((m == 0) ? Qp : Kp) + tbase;
      #pragma unroll
      for (int g = 0; g < 4; ++g) {
        unsigned A0 = cvtpk_bf16(c0[4 * g],     c0[4 * g + 1]);
        unsigned A1 = cvtpk_bf16(c0[4 * g + 2], c0[4 * g + 3]);
        unsigned B0 = cvtpk_bf16(c1[4 * g],     c1[4 * g + 1]);
        unsigned B1 = cvtpk_bf16(c1[4 * g + 2], c1[4 * g + 3]);
        plswap32(A0, B0); plswap32(A1, B1);
        u32x4 u = {A0, A1, B0, B1};
        const int c    = 2 * hi + (g >> 1);
        const int slot = ((g & 1) << 5) + q5;
        *(u32x4*)(dst + ((size_t)c * 64 + slot) * 8) = u;
      }
    } else {
      // V: stage f32 tile in LDS (wave-private), emit packed A-frag stores
      #pragma unroll
      for (int r = 0; r < 16; ++r) {
        const int d = (r & 3) + 8 * (r >> 2) + 4 * hi;
        vtile[wid][q5][d]      = c0[r];
        vtile[wid][q5][d + 32] = c1[r];
      }
      asm volatile("s_waitcnt lgkmcnt(0)" ::: "memory");
      __builtin_amdgcn_sched_barrier(0);
      __bf16* vdst = Vp + tbase + (size_t)l * 8;
      #pragma unroll
      for (int f = 0; f < 4; ++f) {
        const int krow = 16 * (f & 1) + 8 * hi;     // kv row in tile
        const int dcol = q5 + 32 * (f >> 1);        // d column
        u32x4 u;
        #pragma unroll
        for (int ii = 0; ii < 4; ++ii)
          u[ii] = cvtpk_bf16(vtile[wid][krow + 2 * ii][dcol],
                             vtile[wid][krow + 2 * ii + 1][dcol]);
        *(u32x4*)(vdst + (size_t)f * 512) = u;
      }
    }
  }
}

// ---------------------------------------------------------------------------
// attn phase: q-tile t, kv tiles [j0, j1). No-max base-2 softmax (m=0):
// p = exp2(s + kpmS [+ NEGS2 diag mask]); masked -> exactly 0. Accumulates
// acc (unnormalized PV) and lsq (per-lane own-half denominator partial).
// All loads coalesced 16B/lane from fragment-packed Qp/Kp/Vp.
// K regs double-buffered (2x unrolled, no copies).
// ---------------------------------------------------------------------------
static __device__ __forceinline__ void attn_phase(
    const __bf16* __restrict__ qt,     // Qp batch base + t*2048 + l*8
    const __bf16* __restrict__ kB,     // Kp batch base + l*8
    const __bf16* __restrict__ vB,     // Vp batch base + l*8
    const float*  __restrict__ kpb,    // kpmS + b*NCTX
    int T, int j0, int j1, int q5, int hi,
    f32x16& acc0, f32x16& acc1, float& lsq)
{
  if (j0 >= j1) return;

  const bf16x8 qf0 = *(const bf16x8*)(qt);
  const bf16x8 qf1 = *(const bf16x8*)(qt + 512);
  const bf16x8 qf2 = *(const bf16x8*)(qt + 1024);
  const bf16x8 qf3 = *(const bf16x8*)(qt + 1536);

  f32x16 z16;
  #pragma unroll
  for (int r = 0; r < 16; ++r) z16[r] = 0.f;

  bf16x8 kA0, kA1, kA2, kA3, kB0, kB1, kB2, kB3;
  {
    const __bf16* kp = kB + (size_t)j0 * 2048;
    kA0 = *(const bf16x8*)(kp);        kA1 = *(const bf16x8*)(kp + 512);
    kA2 = *(const bf16x8*)(kp + 1024); kA3 = *(const bf16x8*)(kp + 1536);
  }
  int j = j0;

#define ATTN_ITER(KC0, KC1, KC2, KC3, KN0, KN1, KN2, KN3)                   \
  {                                                                         \
    const bool last = (j + 1 >= j1);                                        \
    const bool dg = last && (j1 == T);                                      \
    const __bf16* vp = vB + (size_t)j * 2048;                               \
    const bf16x8 vf0 = *(const bf16x8*)(vp);                                \
    const bf16x8 vf1 = *(const bf16x8*)(vp + 512);                          \
    const bf16x8 vf2 = *(const bf16x8*)(vp + 1024);                         \
    const bf16x8 vf3 = *(const bf16x8*)(vp + 1536);                         \
    const float* kp2 = kpb + j * 32 + 4 * hi;                               \
    f32x4 km[4];                                                            \
    km[0] = *(const f32x4*)(kp2);      km[1] = *(const f32x4*)(kp2 + 8);    \
    km[2] = *(const f32x4*)(kp2 + 16); km[3] = *(const f32x4*)(kp2 + 24);   \
    if (!last) {                                                            \
      const __bf16* kp = kB + (size_t)(j + 1) * 2048;                       \
      KN0 = *(const bf16x8*)(kp);        KN1 = *(const bf16x8*)(kp + 512);  \
      KN2 = *(const bf16x8*)(kp + 1024); KN3 = *(const bf16x8*)(kp + 1536); \
    }                                                                       \
    __builtin_amdgcn_s_setprio(1);                                          \
    f32x16 s = MFMA32(KC0, qf0, z16);                                       \
    s = MFMA32(KC1, qf1, s);                                                \
    s = MFMA32(KC2, qf2, s);                                                \
    s = MFMA32(KC3, qf3, s);                                                \
    __builtin_amdgcn_s_setprio(0);                                          \
    float p[16];                                                            \
    if (dg) {                                                               \
      _Pragma("unroll")                                                     \
      for (int r = 0; r < 16; ++r) {                                        \
        const int rm = (r & 3) + 8 * (r >> 2) + 4 * hi;                     \
        const float tv = s[r] + km[r >> 2][r & 3] + ((rm > q5) ? NEGS2 : 0.f); \
        p[r] = exp2a(tv);                                                   \
      }                                                                     \
    } else {                                                                \
      _Pragma("unroll")                                                     \
      for (int r = 0; r < 16; ++r) p[r] = exp2a(s[r] + km[r >> 2][r & 3]);  \
    }                                                                       \
    lsq += ((p[0] + p[1]) + (p[2] + p[3])) + ((p[4] + p[5]) + (p[6] + p[7]))  \
         + ((p[8] + p[9]) + (p[10] + p[11])) + ((p[12] + p[13]) + (p[14] + p[15])); \
    const bf16x8 pf0 = pack_frag(p[0], p[1], p[2],  p[3],  p[4],  p[5],  p[6],  p[7]);  \
    const bf16x8 pf1 = pack_frag(p[8], p[9], p[10], p[11], p[12], p[13], p[14], p[15]); \
    __builtin_amdgcn_s_setprio(1);                                          \
    acc0 = MFMA32(vf0, pf0, acc0);                                          \
    acc0 = MFMA32(vf1, pf1, acc0);                                          \
    acc1 = MFMA32(vf2, pf0, acc1);                                          \
    acc1 = MFMA32(vf3, pf1, acc1);                                          \
    __builtin_amdgcn_s_setprio(0);                                          \
  }

  for (;;) {
    ATTN_ITER(kA0, kA1, kA2, kA3, kB0, kB1, kB2, kB3);
    if (++j >= j1) break;
    ATTN_ITER(kB0, kB1, kB2, kB3, kA0, kA1, kA2, kA3);
    if (++j >= j1) break;
  }
#undef ATTN_ITER
}

// ---------------------------------------------------------------------------
// Kernel 2: fused split-kv attention + LN + FFN + LN.
// grid = Z*32 x 128 (2 waves). Block tp owns q-tiles t1=tp, t2=63-tp.
// ph=0: wave0 [t1, 0..h1) -> dump; wave1 [t2, h2..T2) -> dump
// ph=1: wave0 [t2, 0..h2) -> keep; wave1 [t1, h1..T1) -> keep
// Every wave ~33 iterations (tail-free). Merge = plain add (no-max softmax
// partials are shift-free). One __syncthreads. Epilogue per wave on kept tile.
// ---------------------------------------------------------------------------
__global__ __launch_bounds__(128) void fused_kernel(
    const __bf16* __restrict__ Qp, const __bf16* __restrict__ Kp,
    const __bf16* __restrict__ Vp, const float* __restrict__ kpmS,
    const float* __restrict__ x,
    const __bf16* __restrict__ w1p, const __bf16* __restrict__ w2p,
    float* __restrict__ out)
{
  const int bid = (blockIdx.x & 7) * 256 + (blockIdx.x >> 3);  // XCD chunking
  const int b   = bid >> 5;
  const int tp  = bid & 31;
  const int wv  = threadIdx.x >> 6;
  const int l   = threadIdx.x & 63;
  const int q5  = l & 31;
  const int hi  = l >> 5;

  const int t1 = tp, t2 = 63 - tp;

  __shared__ float part[2][64][36];   // [wave][lane][acc0|acc1|ls] (stride 36)

  const __bf16* qB = Qp + (size_t)b * (64 * 2048) + (size_t)l * 8;
  const __bf16* kB = Kp + (size_t)b * (64 * 2048) + (size_t)l * 8;
  const __bf16* vB = Vp + (size_t)b * (64 * 2048) + (size_t)l * 8;
  const float*  kpb = kpmS + b * NCTX;

  f32x16 acc0, acc1;
  float lsq;
  #pragma unroll
  for (int r = 0; r < 16; ++r) { acc0[r] = 0.f; acc1[r] = 0.f; }
  lsq = 0.f;

  #pragma unroll
  for (int ph = 0; ph < 2; ++ph) {
    const int t = (wv ^ ph) ? t2 : t1;
    const int T = t + 1;
    const int h = (T + 1) >> 1;
    const int j0 = wv ? h : 0;
    const int j1 = wv ? T : h;
    attn_phase(qB + (size_t)t * 2048, kB, vB, kpb,
               T, j0, j1, q5, hi, acc0, acc1, lsq);
    if (ph == 0) {
      float* ps = &part[wv][l][0];
      #pragma unroll
      for (int g = 0; g < 4; ++g) {
        f32x4 t0, t1v;
        #pragma unroll
        for (int jj = 0; jj < 4; ++jj) { t0[jj] = acc0[4 * g + jj]; t1v[jj] = acc1[4 * g + jj]; }
        *(f32x4*)(ps + 4 * g)      = t0;
        *(f32x4*)(ps + 16 + 4 * g) = t1v;
      }
      ps[32] = lsq;
      #pragma unroll
      for (int r = 0; r < 16; ++r) { acc0[r] = 0.f; acc1[r] = 0.f; }
      lsq = 0.f;
    }
  }
  const int tB = wv ? t1 : t2;

  __syncthreads();

  // ---- merge partner's partial (plain add: no-max softmax) ----
  {
    const float* po = &part[wv ^ 1][l][0];
    #pragma unroll
    for (int g = 0; g < 4; ++g) {
      const f32x4 t0 = *(const f32x4*)(po + 4 * g);
      const f32x4 t1v = *(const f32x4*)(po + 16 + 4 * g);
      #pragma unroll
      for (int jj = 0; jj < 4; ++jj) { acc0[4 * g + jj] += t0[jj]; acc1[4 * g + jj] += t1v[jj]; }
    }
    lsq += po[32];
  }

  // ---- fused epilogue: LN1 + FFN + LN2 on tile tB ----
  const int n = tB * 32 + q5;
  const float invl = 1.f / redsum32(lsq);
  const float* xrow = x + ((size_t)(b * NCTX + n)) * DH;

  f32x16 z16;
  #pragma unroll
  for (int r = 0; r < 16; ++r) z16[r] = 0.f;

  float y0[16], y1[16];
  float s1 = 0.f, s2 = 0.f;
  #pragma unroll
  for (int g = 0; g < 4; ++g) {
    const f32x4 xv0 = *(const f32x4*)(xrow + 8 * g + 4 * hi);
    const f32x4 xv1 = *(const f32x4*)(xrow + 32 + 8 * g + 4 * hi);
    #pragma unroll
    for (int jj = 0; jj < 4; ++jj) {
      const float a0 = acc0[4 * g + jj] * invl + xv0[jj];
      const float a1 = acc1[4 * g + jj] * invl + xv1[jj];
      y0[4 * g + jj] = a0; y1[4 * g + jj] = a1;
      s1 += a0 + a1; s2 += a0 * a0 + a1 * a1;
    }
  }
  s1 = redsum32(s1);
  s2 = redsum32(s2);
  {
    const float mu   = s1 * (1.f / 64.f);
    const float var  = s2 * (1.f / 64.f) - mu * mu;
    const float rstd = rsqrtf(var + 1e-5f);
    #pragma unroll
    for (int r = 0; r < 16; ++r) {
      y0[r] = (y0[r] - mu) * rstd;
      y1[r] = (y1[r] - mu) * rstd;
    }
  }

  const bf16x8 yb0 = pack_frag(y0[0], y0[1], y0[2],  y0[3],  y0[4],  y0[5],  y0[6],  y0[7]);
  const bf16x8 yb1 = pack_frag(y0[8], y0[9], y0[10], y0[11], y0[12], y0[13], y0[14], y0[15]);
  const bf16x8 yb2 = pack_frag(y1[0], y1[1], y1[2],  y1[3],  y1[4],  y1[5],  y1[6],  y1[7]);
  const bf16x8 yb3 = pack_frag(y1[8], y1[9], y1[10], y1[11], y1[12], y1[13], y1[14], y1[15]);

  const __bf16* wp1 = w1p + (size_t)l * 8;
  f32x16 hc;
  hc = MFMA32(*(const bf16x8*)(wp1),              yb0, z16);
  hc = MFMA32(*(const bf16x8*)(wp1 + 64 * 8),     yb1, hc);
  hc = MFMA32(*(const bf16x8*)(wp1 + 2 * 64 * 8), yb2, hc);
  hc = MFMA32(*(const bf16x8*)(wp1 + 3 * 64 * 8), yb3, hc);
  float hv[16];
  #pragma unroll
  for (int r = 0; r < 16; ++r) hv[r] = fmaxf(hc[r], 0.f);

  const bf16x8 hb0 = pack_frag(hv[0], hv[1], hv[2],  hv[3],  hv[4],  hv[5],  hv[6],  hv[7]);
  const bf16x8 hb1 = pack_frag(hv[8], hv[9], hv[10], hv[11], hv[12], hv[13], hv[14], hv[15]);

  const __bf16* wp2 = w2p + (size_t)l * 8;
  f32x16 f20, f21;
  f20 = MFMA32(*(const bf16x8*)(wp2),              hb0, z16);
  f20 = MFMA32(*(const bf16x8*)(wp2 + 64 * 8),     hb1, f20);
  f21 = MFMA32(*(const bf16x8*)(wp2 + 2 * 64 * 8), hb0, z16);
  f21 = MFMA32(*(const bf16x8*)(wp2 + 3 * 64 * 8), hb1, f21);

  float v1 = 0.f, v2 = 0.f;
  float va0[16], va1[16];
  #pragma unroll
  for (int r = 0; r < 16; ++r) {
    va0[r] = f20[r] + y0[r];
    va1[r] = f21[r] + y1[r];
    v1 += va0[r] + va1[r];
    v2 += va0[r] * va0[r] + va1[r] * va1[r];
  }
  v1 = redsum32(v1);
  v2 = redsum32(v2);
  const float mu2   = v1 * (1.f / 64.f);
  const float var2  = v2 * (1.f / 64.f) - mu2 * mu2;
  const float rstd2 = rsqrtf(var2 + 1e-5f);

  float* op = out + ((size_t)(b * NCTX + n)) * DH + 4 * hi;
  #pragma unroll
  for (int g = 0; g < 4; ++g) {
    f32x4 st0, st1;
    #pragma unroll
    for (int jj = 0; jj < 4; ++jj) {
      st0[jj] = (va0[4 * g + jj] - mu2) * rstd2;
      st1[jj] = (va1[4 * g + jj] - mu2) * rstd2;
    }
    *(f32x4*)(op + 8 * g)      = st0;
    *(f32x4*)(op + 32 + 8 * g) = st1;
  }
}

// ---------------------------------------------------------------------------
extern "C" void kernel_launch(void* const* d_in, const int* in_sizes, int n_in,
                              void* d_out, int out_size, void* d_ws, size_t ws_size,
                              hipStream_t stream)
{
  const float* x   = (const float*)d_in[0];
  const float* wq  = (const float*)d_in[1];
  const float* wk  = (const float*)d_in[2];
  const float* wv  = (const float*)d_in[3];
  const float* w1  = (const float*)d_in[4];
  const float* w2  = (const float*)d_in[5];
  const float* kpm = (const float*)d_in[6];
  // d_in[7] = causal_mask: handled structurally (triu(k=1) == -1e9 additive)
  float* out = (float*)d_out;

  char* ws = (char*)d_ws;
  const size_t nelem = (size_t)ZB * NCTX * DH;     // 8388608
  __bf16* Qp   = (__bf16*)(ws);
  __bf16* Kp   = (__bf16*)(ws + nelem * 2);
  __bf16* Vp   = (__bf16*)(ws + nelem * 4);
  float*  kpmS = (float*)(ws + nelem * 6);         // ZB*NCTX f32
  __bf16* w1p  = (__bf16*)(ws + nelem * 6 + (size_t)ZB * NCTX * 4);
  __bf16* w2p  = w1p + 4 * 64 * 8;

  proj_kernel <<<1024, 256, 0, stream>>>(x, wq, wk, wv, w1, w2, kpm,
                                         Qp, Kp, Vp, kpmS, w1p, w2p);
  fused_kernel<<<ZB * 32, 128, 0, stream>>>(Qp, Kp, Vp, kpmS, x, w1p, w2p, out);
}

// Round 12
// 97.416 us; speedup vs baseline: 2.2934x; 1.0734x over previous
//
#include <hip/hip_runtime.h>
#include <cstdint>
#include <cstddef>

// Fused transformer block: out = LN(FFN(LN(attn(x)+x)) + LN(attn(x)+x))
// Z=64, N_CTX=2048, D=64, DFF=32, causal, single head.
// proj: QKV via MFMA -> fragment-packed Qp/Kp/Vp (R10: coalesced 16B/lane).
// fused: split-kv flash attention, no-max base-2 softmax, additive merge.
// R11: (a) kpm loaded as the QK MFMA C-initializer (kills 16 adds + z16);
//      (b) 2-deep software pipeline: QK(j+1) issues before consume(j)'s
//          exp/pack/PV; K(j+2)/km(j+2) prefetch lands mid-consume.

#define ZB   64
#define NCTX 2048
#define DH   64
#define DFF  32
// base-2 softmax: score*SM_SCALE*log2(e); mask -1e9 pre-scale -> NEGS2 in log2 domain
#define SC2   0.18033688011112042f
#define NEGS2 (-1.8033688e8f)

typedef float f32x4  __attribute__((ext_vector_type(4)));
typedef float f32x16 __attribute__((ext_vector_type(16)));
typedef __bf16 bf16x8 __attribute__((ext_vector_type(8)));
typedef unsigned int u32x4 __attribute__((ext_vector_type(4)));

#define MFMA32(a, b, c) __builtin_amdgcn_mfma_f32_32x32x16_bf16((a), (b), (c), 0, 0, 0)

static __device__ __forceinline__ unsigned cvtpk_bf16(float a, float b) {
  unsigned r;
  asm("v_cvt_pk_bf16_f32 %0, %1, %2" : "=v"(r) : "v"(a), "v"(b));
  return r;
}
static __device__ __forceinline__ void plswap32(unsigned &a, unsigned &b) {
  asm volatile("v_permlane32_swap_b32 %0, %1" : "+v"(a), "+v"(b));
}
static __device__ __forceinline__ float exp2a(float x) {
  float r;
  asm("v_exp_f32 %0, %1" : "=v"(r) : "v"(x));
  return r;
}
static __device__ __forceinline__ float redsum32(float v) {
  return v + __shfl_xor(v, 32);   // lane^32; proven-correct path
}
// build a bf16x8 frag ordered {own-half, partner-half} from 8 f32 regs whose
// local row is rm = (r&3) + 8*(r>>2) + 4*hi (the 32x32 C-layout pattern)
static __device__ __forceinline__ bf16x8 pack_frag(
    float v0, float v1, float v2, float v3,
    float v4, float v5, float v6, float v7) {
  unsigned A0 = cvtpk_bf16(v0, v1), A1 = cvtpk_bf16(v2, v3);
  unsigned B0 = cvtpk_bf16(v4, v5), B1 = cvtpk_bf16(v6, v7);
  plswap32(A0, B0); plswap32(A1, B1);
  u32x4 u = {A0, A1, B0, B1};
  return __builtin_bit_cast(bf16x8, u);
}

// ---------------------------------------------------------------------------
// Kernel 1: QKV projection via MFMA (grid 1024 x 256, wave = 32-token tile).
// Outputs in fragment-packed order (frag stride 512 elem, tile stride 2048):
//   Qp/Kp[b][tk][c][l][8]: lane l=(q5,hi') frag c holds Q[tok q5][16c+8hi'+i]
//   Vp[b][tk][f][l][8]: f=(db,kvh); lane l=(d5,hi) holds V[16kvh+8hi+i][d5+32db]
// Q pre-scaled by SC2; kpmS = kpm*SC2; block 0 wave 0 packs w1p/w2p.
// (unchanged from R10 — proven)
// ---------------------------------------------------------------------------
__global__ __launch_bounds__(256) void proj_kernel(
    const float* __restrict__ x, const float* __restrict__ wq,
    const float* __restrict__ wk, const float* __restrict__ wv,
    const float* __restrict__ w1, const float* __restrict__ w2,
    const float* __restrict__ kpm,
    __bf16* __restrict__ Qp, __bf16* __restrict__ Kp, __bf16* __restrict__ Vp,
    float* __restrict__ kpmS, __bf16* __restrict__ w1p, __bf16* __restrict__ w2p)
{
  const int wid = threadIdx.x >> 6;
  const int l   = threadIdx.x & 63;
  const int q5  = l & 31, hi = l >> 5;
  const int tile = blockIdx.x * 4 + wid;        // 4096 tiles of 32 tokens
  const int b   = tile >> 6;                    // 64 tiles per batch
  const int tk  = tile & 63;                    // tile index within batch
  const int n   = (tk << 5) + q5;               // this lane's token

  __shared__ float vtile[4][32][67];            // [wave][token][d], 67: bank-clean

  if (blockIdx.x == 0 && wid == 0) {
    #pragma unroll
    for (int kk = 0; kk < 4; ++kk)
      #pragma unroll
      for (int i = 0; i < 8; ++i)
        w1p[(kk * 64 + l) * 8 + i] = (__bf16)w1[(16 * kk + 8 * hi + i) * DFF + q5];
    #pragma unroll
    for (int dt = 0; dt < 2; ++dt)
      #pragma unroll
      for (int kk2 = 0; kk2 < 2; ++kk2)
        #pragma unroll
        for (int i = 0; i < 8; ++i)
          w2p[((dt * 2 + kk2) * 64 + l) * 8 + i] =
              (__bf16)w2[(16 * kk2 + 8 * hi + i) * DH + 32 * dt + q5];
  }
  if (hi == 0) kpmS[b * NCTX + n] = kpm[b * NCTX + n] * SC2;

  const float* xr = x + ((size_t)(b * NCTX + n)) * DH + 8 * hi;
  bf16x8 xb[4];
  #pragma unroll
  for (int kk = 0; kk < 4; ++kk) {
    const f32x4 a = *(const f32x4*)(xr + 16 * kk);
    const f32x4 c = *(const f32x4*)(xr + 16 * kk + 4);
    u32x4 u = {cvtpk_bf16(a[0], a[1]), cvtpk_bf16(a[2], a[3]),
               cvtpk_bf16(c[0], c[1]), cvtpk_bf16(c[2], c[3])};
    xb[kk] = __builtin_bit_cast(bf16x8, u);
  }

  const size_t tbase = ((size_t)(b * 64 + tk)) * 2048;   // packed tile base

  #pragma unroll
  for (int m = 0; m < 3; ++m) {
    const float* w = (m == 0) ? wq : (m == 1) ? wk : wv;

    f32x16 c0, c1;
    #pragma unroll
    for (int r = 0; r < 16; ++r) { c0[r] = 0.f; c1[r] = 0.f; }

    #pragma unroll
    for (int kk = 0; kk < 4; ++kk) {
      const float* wp = w + (size_t)(16 * kk + 8 * hi) * DH + q5;
      float f0[8], f1[8];
      #pragma unroll
      for (int i = 0; i < 8; ++i) { f0[i] = wp[i * DH]; f1[i] = wp[i * DH + 32]; }
      u32x4 ua = {cvtpk_bf16(f0[0], f0[1]), cvtpk_bf16(f0[2], f0[3]),
                  cvtpk_bf16(f0[4], f0[5]), cvtpk_bf16(f0[6], f0[7])};
      u32x4 ub = {cvtpk_bf16(f1[0], f1[1]), cvtpk_bf16(f1[2], f1[3]),
                  cvtpk_bf16(f1[4], f1[5]), cvtpk_bf16(f1[6], f1[7])};
      c0 = MFMA32(__builtin_bit_cast(bf16x8, ua), xb[kk], c0);
      c1 = MFMA32(__builtin_bit_cast(bf16x8, ub), xb[kk], c1);
    }

    if (m == 0) {
      #pragma unroll
      for (int r = 0; r < 16; ++r) { c0[r] *= SC2; c1[r] *= SC2; }
    }

    if (m < 2) {
      // frag c = 2hi + (g>>1), slot = (g&1)*32 + q5 (verified R10)
      __bf16* dst = ((m == 0) ? Qp : Kp) + tbase;
      #pragma unroll
      for (int g = 0; g < 4; ++g) {
        unsigned A0 = cvtpk_bf16(c0[4 * g],     c0[4 * g + 1]);
        unsigned A1 = cvtpk_bf16(c0[4 * g + 2], c0[4 * g + 3]);
        unsigned B0 = cvtpk_bf16(c1[4 * g],     c1[4 * g + 1]);
        unsigned B1 = cvtpk_bf16(c1[4 * g + 2], c1[4 * g + 3]);
        plswap32(A0, B0); plswap32(A1, B1);
        u32x4 u = {A0, A1, B0, B1};
        const int c    = 2 * hi + (g >> 1);
        const int slot = ((g & 1) << 5) + q5;
        *(u32x4*)(dst + ((size_t)c * 64 + slot) * 8) = u;
      }
    } else {
      // V: stage f32 tile in LDS (wave-private), emit packed A-frag stores
      #pragma unroll
      for (int r = 0; r < 16; ++r) {
        const int d = (r & 3) + 8 * (r >> 2) + 4 * hi;
        vtile[wid][q5][d]      = c0[r];
        vtile[wid][q5][d + 32] = c1[r];
      }
      asm volatile("s_waitcnt lgkmcnt(0)" ::: "memory");
      __builtin_amdgcn_sched_barrier(0);
      __bf16* vdst = Vp + tbase + (size_t)l * 8;
      #pragma unroll
      for (int f = 0; f < 4; ++f) {
        const int krow = 16 * (f & 1) + 8 * hi;     // kv row in tile
        const int dcol = q5 + 32 * (f >> 1);        // d column
        u32x4 u;
        #pragma unroll
        for (int ii = 0; ii < 4; ++ii)
          u[ii] = cvtpk_bf16(vtile[wid][krow + 2 * ii][dcol],
                             vtile[wid][krow + 2 * ii + 1][dcol]);
        *(u32x4*)(vdst + (size_t)f * 512) = u;
      }
    }
  }
}

// ---------------------------------------------------------------------------
// attn phase: q-tile t, kv tiles [j0, j1), 2-deep pipelined.
// Invariant at loop top: sX = scores(j) ready; kY = K(j+1); sY = km(j+1).
// Body: QK(j+1) into MFMA pipe -> consume(j): V loads, exp (frees sX),
// prefetch K(j+2)+km(j+2) into (kX, sX), sum, pack, PV. Diag mask only in
// the tail consume. km rides in the score buffer as the MFMA C-init.
// ---------------------------------------------------------------------------
static __device__ __forceinline__ void attn_phase(
    const __bf16* __restrict__ qt,     // Qp batch base + t*2048 + l*8
    const __bf16* __restrict__ kBp,    // Kp batch base + l*8
    const __bf16* __restrict__ vBp,    // Vp batch base + l*8
    const float*  __restrict__ kpb,    // kpmS + b*NCTX
    int T, int j0, int j1, int q5, int hi,
    f32x16& acc0, f32x16& acc1, float& lsq)
{
  if (j0 >= j1) return;

  const bf16x8 qf0 = *(const bf16x8*)(qt);
  const bf16x8 qf1 = *(const bf16x8*)(qt + 512);
  const bf16x8 qf2 = *(const bf16x8*)(qt + 1024);
  const bf16x8 qf3 = *(const bf16x8*)(qt + 1536);

  bf16x8 kA0, kA1, kA2, kA3, kB0, kB1, kB2, kB3;
  f32x16 sA, sB;

#define LOADK(P0, P1, P2, P3, J) do {                                       \
    const __bf16* _kp = kBp + (size_t)(J) * 2048;                           \
    P0 = *(const bf16x8*)(_kp);        P1 = *(const bf16x8*)(_kp + 512);    \
    P2 = *(const bf16x8*)(_kp + 1024); P3 = *(const bf16x8*)(_kp + 1536);   \
  } while (0)

#define KMLD(S, J) do {                                                     \
    const float* _mp = kpb + (J) * 32 + 4 * hi;                             \
    const f32x4 _m0 = *(const f32x4*)(_mp);                                 \
    const f32x4 _m1 = *(const f32x4*)(_mp + 8);                             \
    const f32x4 _m2 = *(const f32x4*)(_mp + 16);                            \
    const f32x4 _m3 = *(const f32x4*)(_mp + 24);                            \
    _Pragma("unroll")                                                       \
    for (int _jj = 0; _jj < 4; ++_jj) {                                     \
      S[_jj] = _m0[_jj];      S[4 + _jj] = _m1[_jj];                        \
      S[8 + _jj] = _m2[_jj];  S[12 + _jj] = _m3[_jj];                       \
    }                                                                       \
  } while (0)

#define QKP(S, P0, P1, P2, P3) do {                                         \
    __builtin_amdgcn_s_setprio(1);                                          \
    S = MFMA32(P0, qf0, S);                                                 \
    S = MFMA32(P1, qf1, S);                                                 \
    S = MFMA32(P2, qf2, S);                                                 \
    S = MFMA32(P3, qf3, S);                                                 \
    __builtin_amdgcn_s_setprio(0);                                          \
  } while (0)

// consume scores in S for kv-tile J; if PF, prefetch K(jn)->PK*, km(jn)->S
#define CONSUME(S, J, DG, PF, PK0, PK1, PK2, PK3) do {                      \
    const __bf16* _vp = vBp + (size_t)(J) * 2048;                           \
    const bf16x8 vf0 = *(const bf16x8*)(_vp);                               \
    const bf16x8 vf1 = *(const bf16x8*)(_vp + 512);                         \
    const bf16x8 vf2 = *(const bf16x8*)(_vp + 1024);                        \
    const bf16x8 vf3 = *(const bf16x8*)(_vp + 1536);                        \
    float p[16];                                                            \
    if (DG) {                                                               \
      _Pragma("unroll")                                                     \
      for (int r = 0; r < 16; ++r) {                                        \
        const int rm = (r & 3) + 8 * (r >> 2) + 4 * hi;                     \
        p[r] = exp2a((rm > q5) ? S[r] + NEGS2 : S[r]);                      \
      }                                                                     \
    } else {                                                                \
      _Pragma("unroll")                                                     \
      for (int r = 0; r < 16; ++r) p[r] = exp2a(S[r]);                      \
    }                                                                       \
    if (PF) {                                                               \
      const int _jn = ((J) + 2 < j1) ? (J) + 2 : j1 - 1;                    \
      LOADK(PK0, PK1, PK2, PK3, _jn);                                       \
      KMLD(S, _jn);                                                         \
    }                                                                       \
    lsq += ((p[0] + p[1]) + (p[2] + p[3])) + ((p[4] + p[5]) + (p[6] + p[7]))  \
         + ((p[8] + p[9]) + (p[10] + p[11])) + ((p[12] + p[13]) + (p[14] + p[15])); \
    const bf16x8 pf0 = pack_frag(p[0], p[1], p[2],  p[3],  p[4],  p[5],  p[6],  p[7]);  \
    const bf16x8 pf1 = pack_frag(p[8], p[9], p[10], p[11], p[12], p[13], p[14], p[15]); \
    __builtin_amdgcn_s_setprio(1);                                          \
    acc0 = MFMA32(vf0, pf0, acc0);                                          \
    acc0 = MFMA32(vf1, pf1, acc0);                                          \
    acc1 = MFMA32(vf2, pf0, acc1);                                          \
    acc1 = MFMA32(vf3, pf1, acc1);                                          \
    __builtin_amdgcn_s_setprio(0);                                          \
  } while (0)

  LOADK(kA0, kA1, kA2, kA3, j0);
  KMLD(sA, j0);
  QKP(sA, kA0, kA1, kA2, kA3);
  if (j1 - j0 == 1) {
    CONSUME(sA, j0, (j1 == T), false, kB0, kB1, kB2, kB3);
  } else {
    LOADK(kB0, kB1, kB2, kB3, j0 + 1);
    KMLD(sB, j0 + 1);
    int j = j0;
    for (;;) {
      QKP(sB, kB0, kB1, kB2, kB3);                       // scores(j+1)
      CONSUME(sA, j, false, true, kA0, kA1, kA2, kA3);   // consume j, pf j+2
      ++j;
      if (j + 1 >= j1) { CONSUME(sB, j, (j1 == T), false, kA0, kA1, kA2, kA3); break; }
      QKP(sA, kA0, kA1, kA2, kA3);
      CONSUME(sB, j, false, true, kB0, kB1, kB2, kB3);
      ++j;
      if (j + 1 >= j1) { CONSUME(sA, j, (j1 == T), false, kB0, kB1, kB2, kB3); break; }
    }
  }
#undef LOADK
#undef KMLD
#undef QKP
#undef CONSUME
}

// ---------------------------------------------------------------------------
// Kernel 2: fused split-kv attention + LN + FFN + LN.
// grid = Z*32 x 128 (2 waves). Block tp owns q-tiles t1=tp, t2=63-tp.
// ph=0: wave0 [t1, 0..h1) -> dump; wave1 [t2, h2..T2) -> dump
// ph=1: wave0 [t2, 0..h2) -> keep; wave1 [t1, h1..T1) -> keep
// Every wave ~33 iterations (tail-free). Merge = plain add (no-max softmax
// partials are shift-free). One __syncthreads. Epilogue per wave on kept tile.
// ---------------------------------------------------------------------------
__global__ __launch_bounds__(128) void fused_kernel(
    const __bf16* __restrict__ Qp, const __bf16* __restrict__ Kp,
    const __bf16* __restrict__ Vp, const float* __restrict__ kpmS,
    const float* __restrict__ x,
    const __bf16* __restrict__ w1p, const __bf16* __restrict__ w2p,
    float* __restrict__ out)
{
  const int bid = (blockIdx.x & 7) * 256 + (blockIdx.x >> 3);  // XCD chunking
  const int b   = bid >> 5;
  const int tp  = bid & 31;
  const int wv  = threadIdx.x >> 6;
  const int l   = threadIdx.x & 63;
  const int q5  = l & 31;
  const int hi  = l >> 5;

  const int t1 = tp, t2 = 63 - tp;

  __shared__ float part[2][64][36];   // [wave][lane][acc0|acc1|ls] (stride 36)

  const __bf16* qB = Qp + (size_t)b * (64 * 2048) + (size_t)l * 8;
  const __bf16* kB = Kp + (size_t)b * (64 * 2048) + (size_t)l * 8;
  const __bf16* vB = Vp + (size_t)b * (64 * 2048) + (size_t)l * 8;
  const float*  kpb = kpmS + b * NCTX;

  f32x16 acc0, acc1;
  float lsq;
  #pragma unroll
  for (int r = 0; r < 16; ++r) { acc0[r] = 0.f; acc1[r] = 0.f; }
  lsq = 0.f;

  #pragma unroll
  for (int ph = 0; ph < 2; ++ph) {
    const int t = (wv ^ ph) ? t2 : t1;
    const int T = t + 1;
    const int h = (T + 1) >> 1;
    const int j0 = wv ? h : 0;
    const int j1 = wv ? T : h;
    attn_phase(qB + (size_t)t * 2048, kB, vB, kpb,
               T, j0, j1, q5, hi, acc0, acc1, lsq);
    if (ph == 0) {
      float* ps = &part[wv][l][0];
      #pragma unroll
      for (int g = 0; g < 4; ++g) {
        f32x4 t0, t1v;
        #pragma unroll
        for (int jj = 0; jj < 4; ++jj) { t0[jj] = acc0[4 * g + jj]; t1v[jj] = acc1[4 * g + jj]; }
        *(f32x4*)(ps + 4 * g)      = t0;
        *(f32x4*)(ps + 16 + 4 * g) = t1v;
      }
      ps[32] = lsq;
      #pragma unroll
      for (int r = 0; r < 16; ++r) { acc0[r] = 0.f; acc1[r] = 0.f; }
      lsq = 0.f;
    }
  }
  const int tB = wv ? t1 : t2;

  __syncthreads();

  // ---- merge partner's partial (plain add: no-max softmax) ----
  {
    const float* po = &part[wv ^ 1][l][0];
    #pragma unroll
    for (int g = 0; g < 4; ++g) {
      const f32x4 t0 = *(const f32x4*)(po + 4 * g);
      const f32x4 t1v = *(const f32x4*)(po + 16 + 4 * g);
      #pragma unroll
      for (int jj = 0; jj < 4; ++jj) { acc0[4 * g + jj] += t0[jj]; acc1[4 * g + jj] += t1v[jj]; }
    }
    lsq += po[32];
  }

  // ---- fused epilogue: LN1 + FFN + LN2 on tile tB ----
  const int n = tB * 32 + q5;
  const float invl = 1.f / redsum32(lsq);
  const float* xrow = x + ((size_t)(b * NCTX + n)) * DH;

  f32x16 z16;
  #pragma unroll
  for (int r = 0; r < 16; ++r) z16[r] = 0.f;

  float y0[16], y1[16];
  float s1 = 0.f, s2 = 0.f;
  #pragma unroll
  for (int g = 0; g < 4; ++g) {
    const f32x4 xv0 = *(const f32x4*)(xrow + 8 * g + 4 * hi);
    const f32x4 xv1 = *(const f32x4*)(xrow + 32 + 8 * g + 4 * hi);
    #pragma unroll
    for (int jj = 0; jj < 4; ++jj) {
      const float a0 = acc0[4 * g + jj] * invl + xv0[jj];
      const float a1 = acc1[4 * g + jj] * invl + xv1[jj];
      y0[4 * g + jj] = a0; y1[4 * g + jj] = a1;
      s1 += a0 + a1; s2 += a0 * a0 + a1 * a1;
    }
  }
  s1 = redsum32(s1);
  s2 = redsum32(s2);
  {
    const float mu   = s1 * (1.f / 64.f);
    const float var  = s2 * (1.f / 64.f) - mu * mu;
    const float rstd = rsqrtf(var + 1e-5f);
    #pragma unroll
    for (int r = 0; r < 16; ++r) {
      y0[r] = (y0[r] - mu) * rstd;
      y1[r] = (y1[r] - mu) * rstd;
    }
  }

  const bf16x8 yb0 = pack_frag(y0[0], y0[1], y0[2],  y0[3],  y0[4],  y0[5],  y0[6],  y0[7]);
  const bf16x8 yb1 = pack_frag(y0[8], y0[9], y0[10], y0[11], y0[12], y0[13], y0[14], y0[15]);
  const bf16x8 yb2 = pack_frag(y1[0], y1[1], y1[2],  y1[3],  y1[4],  y1[5],  y1[6],  y1[7]);
  const bf16x8 yb3 = pack_frag(y1[8], y1[9], y1[10], y1[11], y1[12], y1[13], y1[14], y1[15]);

  const __bf16* wp1 = w1p + (size_t)l * 8;
  f32x16 hc;
  hc = MFMA32(*(const bf16x8*)(wp1),              yb0, z16);
  hc = MFMA32(*(const bf16x8*)(wp1 + 64 * 8),     yb1, hc);
  hc = MFMA32(*(const bf16x8*)(wp1 + 2 * 64 * 8), yb2, hc);
  hc = MFMA32(*(const bf16x8*)(wp1 + 3 * 64 * 8), yb3, hc);
  float hv[16];
  #pragma unroll
  for (int r = 0; r < 16; ++r) hv[r] = fmaxf(hc[r], 0.f);

  const bf16x8 hb0 = pack_frag(hv[0], hv[1], hv[2],  hv[3],  hv[4],  hv[5],  hv[6],  hv[7]);
  const bf16x8 hb1 = pack_frag(hv[8], hv[9], hv[10], hv[11], hv[12], hv[13], hv[14], hv[15]);

  const __bf16* wp2 = w2p + (size_t)l * 8;
  f32x16 f20, f21;
  f20 = MFMA32(*(const bf16x8*)(wp2),              hb0, z16);
  f20 = MFMA32(*(const bf16x8*)(wp2 + 64 * 8),     hb1, f20);
  f21 = MFMA32(*(const bf16x8*)(wp2 + 2 * 64 * 8), hb0, z16);
  f21 = MFMA32(*(const bf16x8*)(wp2 + 3 * 64 * 8), hb1, f21);

  float v1 = 0.f, v2 = 0.f;
  float va0[16], va1[16];
  #pragma unroll
  for (int r = 0; r < 16; ++r) {
    va0[r] = f20[r] + y0[r];
    va1[r] = f21[r] + y1[r];
    v1 += va0[r] + va1[r];
    v2 += va0[r] * va0[r] + va1[r] * va1[r];
  }
  v1 = redsum32(v1);
  v2 = redsum32(v2);
  const float mu2   = v1 * (1.f / 64.f);
  const float var2  = v2 * (1.f / 64.f) - mu2 * mu2;
  const float rstd2 = rsqrtf(var2 + 1e-5f);

  float* op = out + ((size_t)(b * NCTX + n)) * DH + 4 * hi;
  #pragma unroll
  for (int g = 0; g < 4; ++g) {
    f32x4 st0, st1;
    #pragma unroll
    for (int jj = 0; jj < 4; ++jj) {
      st0[jj] = (va0[4 * g + jj] - mu2) * rstd2;
      st1[jj] = (va1[4 * g + jj] - mu2) * rstd2;
    }
    *(f32x4*)(op + 8 * g)      = st0;
    *(f32x4*)(op + 32 + 8 * g) = st1;
  }
}

// ---------------------------------------------------------------------------
extern "C" void kernel_launch(void* const* d_in, const int* in_sizes, int n_in,
                              void* d_out, int out_size, void* d_ws, size_t ws_size,
                              hipStream_t stream)
{
  const float* x   = (const float*)d_in[0];
  const float* wq  = (const float*)d_in[1];
  const float* wk  = (const float*)d_in[2];
  const float* wv  = (const float*)d_in[3];
  const float* w1  = (const float*)d_in[4];
  const float* w2  = (const float*)d_in[5];
  const float* kpm = (const float*)d_in[6];
  // d_in[7] = causal_mask: handled structurally (triu(k=1) == -1e9 additive)
  float* out = (float*)d_out;

  char* ws = (char*)d_ws;
  const size_t nelem = (size_t)ZB * NCTX * DH;     // 8388608
  __bf16* Qp   = (__bf16*)(ws);
  __bf16* Kp   = (__bf16*)(ws + nelem * 2);
  __bf16* Vp   = (__bf16*)(ws + nelem * 4);
  float*  kpmS = (float*)(ws + nelem * 6);         // ZB*NCTX f32
  __bf16* w1p  = (__bf16*)(ws + nelem * 6 + (size_t)ZB * NCTX * 4);
  __bf16* w2p  = w1p + 4 * 64 * 8;

  proj_kernel <<<1024, 256, 0, stream>>>(x, wq, wk, wv, w1, w2, kpm,
                                         Qp, Kp, Vp, kpmS, w1p, w2p);
  fused_kernel<<<ZB * 32, 128, 0, stream>>>(Qp, Kp, Vp, kpmS, x, w1p, w2p, out);
}

// Round 13
// 97.143 us; speedup vs baseline: 2.2998x; 1.0028x over previous
//
#include <hip/hip_runtime.h>
#include <cstdint>
#include <cstddef>

// Fused transformer block: out = LN(FFN(LN(attn(x)+x)) + LN(attn(x)+x))
// Z=64, N_CTX=2048, D=64, DFF=32, causal, single head.
// proj: QKV via MFMA -> fragment-packed Qp/Kp/Vp (R10: coalesced 16B/lane).
// fused: split-kv flash attention, no-max base-2 softmax, additive merge.
// R11: kpm as QK C-init; 2-deep K/km pipeline.
// R13: V double-buffered too — V(j+1) issues at top of consume(j), giving
//      its L2 latency ~400cy of cover (consume VALU + next QKP). VGPR ~128.

#define ZB   64
#define NCTX 2048
#define DH   64
#define DFF  32
// base-2 softmax: score*SM_SCALE*log2(e); mask -1e9 pre-scale -> NEGS2 in log2 domain
#define SC2   0.18033688011112042f
#define NEGS2 (-1.8033688e8f)

typedef float f32x4  __attribute__((ext_vector_type(4)));
typedef float f32x16 __attribute__((ext_vector_type(16)));
typedef __bf16 bf16x8 __attribute__((ext_vector_type(8)));
typedef unsigned int u32x4 __attribute__((ext_vector_type(4)));

#define MFMA32(a, b, c) __builtin_amdgcn_mfma_f32_32x32x16_bf16((a), (b), (c), 0, 0, 0)

static __device__ __forceinline__ unsigned cvtpk_bf16(float a, float b) {
  unsigned r;
  asm("v_cvt_pk_bf16_f32 %0, %1, %2" : "=v"(r) : "v"(a), "v"(b));
  return r;
}
static __device__ __forceinline__ void plswap32(unsigned &a, unsigned &b) {
  asm volatile("v_permlane32_swap_b32 %0, %1" : "+v"(a), "+v"(b));
}
static __device__ __forceinline__ float exp2a(float x) {
  float r;
  asm("v_exp_f32 %0, %1" : "=v"(r) : "v"(x));
  return r;
}
static __device__ __forceinline__ float redsum32(float v) {
  return v + __shfl_xor(v, 32);   // lane^32; proven-correct path
}
// build a bf16x8 frag ordered {own-half, partner-half} from 8 f32 regs whose
// local row is rm = (r&3) + 8*(r>>2) + 4*hi (the 32x32 C-layout pattern)
static __device__ __forceinline__ bf16x8 pack_frag(
    float v0, float v1, float v2, float v3,
    float v4, float v5, float v6, float v7) {
  unsigned A0 = cvtpk_bf16(v0, v1), A1 = cvtpk_bf16(v2, v3);
  unsigned B0 = cvtpk_bf16(v4, v5), B1 = cvtpk_bf16(v6, v7);
  plswap32(A0, B0); plswap32(A1, B1);
  u32x4 u = {A0, A1, B0, B1};
  return __builtin_bit_cast(bf16x8, u);
}

// ---------------------------------------------------------------------------
// Kernel 1: QKV projection via MFMA (grid 1024 x 256, wave = 32-token tile).
// Outputs in fragment-packed order (frag stride 512 elem, tile stride 2048):
//   Qp/Kp[b][tk][c][l][8]: lane l=(q5,hi') frag c holds Q[tok q5][16c+8hi'+i]
//   Vp[b][tk][f][l][8]: f=(db,kvh); lane l=(d5,hi) holds V[16kvh+8hi+i][d5+32db]
// Q pre-scaled by SC2; kpmS = kpm*SC2; block 0 wave 0 packs w1p/w2p.
// (unchanged from R10 — proven)
// ---------------------------------------------------------------------------
__global__ __launch_bounds__(256) void proj_kernel(
    const float* __restrict__ x, const float* __restrict__ wq,
    const float* __restrict__ wk, const float* __restrict__ wv,
    const float* __restrict__ w1, const float* __restrict__ w2,
    const float* __restrict__ kpm,
    __bf16* __restrict__ Qp, __bf16* __restrict__ Kp, __bf16* __restrict__ Vp,
    float* __restrict__ kpmS, __bf16* __restrict__ w1p, __bf16* __restrict__ w2p)
{
  const int wid = threadIdx.x >> 6;
  const int l   = threadIdx.x & 63;
  const int q5  = l & 31, hi = l >> 5;
  const int tile = blockIdx.x * 4 + wid;        // 4096 tiles of 32 tokens
  const int b   = tile >> 6;                    // 64 tiles per batch
  const int tk  = tile & 63;                    // tile index within batch
  const int n   = (tk << 5) + q5;               // this lane's token

  __shared__ float vtile[4][32][67];            // [wave][token][d], 67: bank-clean

  if (blockIdx.x == 0 && wid == 0) {
    #pragma unroll
    for (int kk = 0; kk < 4; ++kk)
      #pragma unroll
      for (int i = 0; i < 8; ++i)
        w1p[(kk * 64 + l) * 8 + i] = (__bf16)w1[(16 * kk + 8 * hi + i) * DFF + q5];
    #pragma unroll
    for (int dt = 0; dt < 2; ++dt)
      #pragma unroll
      for (int kk2 = 0; kk2 < 2; ++kk2)
        #pragma unroll
        for (int i = 0; i < 8; ++i)
          w2p[((dt * 2 + kk2) * 64 + l) * 8 + i] =
              (__bf16)w2[(16 * kk2 + 8 * hi + i) * DH + 32 * dt + q5];
  }
  if (hi == 0) kpmS[b * NCTX + n] = kpm[b * NCTX + n] * SC2;

  const float* xr = x + ((size_t)(b * NCTX + n)) * DH + 8 * hi;
  bf16x8 xb[4];
  #pragma unroll
  for (int kk = 0; kk < 4; ++kk) {
    const f32x4 a = *(const f32x4*)(xr + 16 * kk);
    const f32x4 c = *(const f32x4*)(xr + 16 * kk + 4);
    u32x4 u = {cvtpk_bf16(a[0], a[1]), cvtpk_bf16(a[2], a[3]),
               cvtpk_bf16(c[0], c[1]), cvtpk_bf16(c[2], c[3])};
    xb[kk] = __builtin_bit_cast(bf16x8, u);
  }

  const size_t tbase = ((size_t)(b * 64 + tk)) * 2048;   // packed tile base

  #pragma unroll
  for (int m = 0; m < 3; ++m) {
    const float* w = (m == 0) ? wq : (m == 1) ? wk : wv;

    f32x16 c0, c1;
    #pragma unroll
    for (int r = 0; r < 16; ++r) { c0[r] = 0.f; c1[r] = 0.f; }

    #pragma unroll
    for (int kk = 0; kk < 4; ++kk) {
      const float* wp = w + (size_t)(16 * kk + 8 * hi) * DH + q5;
      float f0[8], f1[8];
      #pragma unroll
      for (int i = 0; i < 8; ++i) { f0[i] = wp[i * DH]; f1[i] = wp[i * DH + 32]; }
      u32x4 ua = {cvtpk_bf16(f0[0], f0[1]), cvtpk_bf16(f0[2], f0[3]),
                  cvtpk_bf16(f0[4], f0[5]), cvtpk_bf16(f0[6], f0[7])};
      u32x4 ub = {cvtpk_bf16(f1[0], f1[1]), cvtpk_bf16(f1[2], f1[3]),
                  cvtpk_bf16(f1[4], f1[5]), cvtpk_bf16(f1[6], f1[7])};
      c0 = MFMA32(__builtin_bit_cast(bf16x8, ua), xb[kk], c0);
      c1 = MFMA32(__builtin_bit_cast(bf16x8, ub), xb[kk], c1);
    }

    if (m == 0) {
      #pragma unroll
      for (int r = 0; r < 16; ++r) { c0[r] *= SC2; c1[r] *= SC2; }
    }

    if (m < 2) {
      // frag c = 2hi + (g>>1), slot = (g&1)*32 + q5 (verified R10)
      __bf16* dst = ((m == 0) ? Qp : Kp) + tbase;
      #pragma unroll
      for (int g = 0; g < 4; ++g) {
        unsigned A0 = cvtpk_bf16(c0[4 * g],     c0[4 * g + 1]);
        unsigned A1 = cvtpk_bf16(c0[4 * g + 2], c0[4 * g + 3]);
        unsigned B0 = cvtpk_bf16(c1[4 * g],     c1[4 * g + 1]);
        unsigned B1 = cvtpk_bf16(c1[4 * g + 2], c1[4 * g + 3]);
        plswap32(A0, B0); plswap32(A1, B1);
        u32x4 u = {A0, A1, B0, B1};
        const int c    = 2 * hi + (g >> 1);
        const int slot = ((g & 1) << 5) + q5;
        *(u32x4*)(dst + ((size_t)c * 64 + slot) * 8) = u;
      }
    } else {
      // V: stage f32 tile in LDS (wave-private), emit packed A-frag stores
      #pragma unroll
      for (int r = 0; r < 16; ++r) {
        const int d = (r & 3) + 8 * (r >> 2) + 4 * hi;
        vtile[wid][q5][d]      = c0[r];
        vtile[wid][q5][d + 32] = c1[r];
      }
      asm volatile("s_waitcnt lgkmcnt(0)" ::: "memory");
      __builtin_amdgcn_sched_barrier(0);
      __bf16* vdst = Vp + tbase + (size_t)l * 8;
      #pragma unroll
      for (int f = 0; f < 4; ++f) {
        const int krow = 16 * (f & 1) + 8 * hi;     // kv row in tile
        const int dcol = q5 + 32 * (f >> 1);        // d column
        u32x4 u;
        #pragma unroll
        for (int ii = 0; ii < 4; ++ii)
          u[ii] = cvtpk_bf16(vtile[wid][krow + 2 * ii][dcol],
                             vtile[wid][krow + 2 * ii + 1][dcol]);
        *(u32x4*)(vdst + (size_t)f * 512) = u;
      }
    }
  }
}

// ---------------------------------------------------------------------------
// attn phase: q-tile t, kv tiles [j0, j1), fully 2-deep pipelined (K, km, V).
// Loop-top invariant: sX = scores(j) ready; kY = K(j+1); sY = km(j+1);
// vX = V(j). Body: QK(j+1) -> consume(j): issue V(j+1)->vY, exp (frees sX),
// prefetch K(j+2)->kX + km(j+2)->sX, sum, pack, PV with vX. Diag mask only
// in the tail consume. km rides in the score buffer as the MFMA C-init.
// ---------------------------------------------------------------------------
static __device__ __forceinline__ void attn_phase(
    const __bf16* __restrict__ qt,     // Qp batch base + t*2048 + l*8
    const __bf16* __restrict__ kBp,    // Kp batch base + l*8
    const __bf16* __restrict__ vBp,    // Vp batch base + l*8
    const float*  __restrict__ kpb,    // kpmS + b*NCTX
    int T, int j0, int j1, int q5, int hi,
    f32x16& acc0, f32x16& acc1, float& lsq)
{
  if (j0 >= j1) return;

  const bf16x8 qf0 = *(const bf16x8*)(qt);
  const bf16x8 qf1 = *(const bf16x8*)(qt + 512);
  const bf16x8 qf2 = *(const bf16x8*)(qt + 1024);
  const bf16x8 qf3 = *(const bf16x8*)(qt + 1536);

  bf16x8 kA0, kA1, kA2, kA3, kB0, kB1, kB2, kB3;
  bf16x8 vA0, vA1, vA2, vA3, vB0, vB1, vB2, vB3;
  f32x16 sA, sB;

#define LOADK(P0, P1, P2, P3, J) do {                                       \
    const __bf16* _kp = kBp + (size_t)(J) * 2048;                           \
    P0 = *(const bf16x8*)(_kp);        P1 = *(const bf16x8*)(_kp + 512);    \
    P2 = *(const bf16x8*)(_kp + 1024); P3 = *(const bf16x8*)(_kp + 1536);   \
  } while (0)

#define LOADV(P0, P1, P2, P3, J) do {                                       \
    const __bf16* _vp = vBp + (size_t)(J) * 2048;                           \
    P0 = *(const bf16x8*)(_vp);        P1 = *(const bf16x8*)(_vp + 512);    \
    P2 = *(const bf16x8*)(_vp + 1024); P3 = *(const bf16x8*)(_vp + 1536);   \
  } while (0)

#define KMLD(S, J) do {                                                     \
    const float* _mp = kpb + (J) * 32 + 4 * hi;                             \
    const f32x4 _m0 = *(const f32x4*)(_mp);                                 \
    const f32x4 _m1 = *(const f32x4*)(_mp + 8);                             \
    const f32x4 _m2 = *(const f32x4*)(_mp + 16);                            \
    const f32x4 _m3 = *(const f32x4*)(_mp + 24);                            \
    _Pragma("unroll")                                                       \
    for (int _jj = 0; _jj < 4; ++_jj) {                                     \
      S[_jj] = _m0[_jj];      S[4 + _jj] = _m1[_jj];                        \
      S[8 + _jj] = _m2[_jj];  S[12 + _jj] = _m3[_jj];                       \
    }                                                                       \
  } while (0)

#define QKP(S, P0, P1, P2, P3) do {                                         \
    __builtin_amdgcn_s_setprio(1);                                          \
    S = MFMA32(P0, qf0, S);                                                 \
    S = MFMA32(P1, qf1, S);                                                 \
    S = MFMA32(P2, qf2, S);                                                 \
    S = MFMA32(P3, qf3, S);                                                 \
    __builtin_amdgcn_s_setprio(0);                                          \
  } while (0)

// pipelined consume of scores S for tile J (never diagonal): issue V(J+1)
// into VN*, exp, prefetch K(clamp(J+2))->PK* and km->S, sum, pack, PV w/ VC*.
#define CONSUME_P(S, J, PK0, PK1, PK2, PK3, VN0, VN1, VN2, VN3,             \
                  VC0, VC1, VC2, VC3) do {                                  \
    LOADV(VN0, VN1, VN2, VN3, (J) + 1);                                     \
    float p[16];                                                            \
    _Pragma("unroll")                                                       \
    for (int r = 0; r < 16; ++r) p[r] = exp2a(S[r]);                        \
    {                                                                       \
      const int _jn = ((J) + 2 < j1) ? (J) + 2 : j1 - 1;                    \
      LOADK(PK0, PK1, PK2, PK3, _jn);                                       \
      KMLD(S, _jn);                                                         \
    }                                                                       \
    lsq += ((p[0] + p[1]) + (p[2] + p[3])) + ((p[4] + p[5]) + (p[6] + p[7]))  \
         + ((p[8] + p[9]) + (p[10] + p[11])) + ((p[12] + p[13]) + (p[14] + p[15])); \
    const bf16x8 pf0 = pack_frag(p[0], p[1], p[2],  p[3],  p[4],  p[5],  p[6],  p[7]);  \
    const bf16x8 pf1 = pack_frag(p[8], p[9], p[10], p[11], p[12], p[13], p[14], p[15]); \
    __builtin_amdgcn_s_setprio(1);                                          \
    acc0 = MFMA32(VC0, pf0, acc0);                                          \
    acc0 = MFMA32(VC1, pf1, acc0);                                          \
    acc1 = MFMA32(VC2, pf0, acc1);                                          \
    acc1 = MFMA32(VC3, pf1, acc1);                                          \
    __builtin_amdgcn_s_setprio(0);                                          \
  } while (0)

// tail consume (no prefetch; optional diagonal mask), PV with VC*.
#define CONSUME_T(S, DG, VC0, VC1, VC2, VC3) do {                           \
    float p[16];                                                            \
    if (DG) {                                                               \
      _Pragma("unroll")                                                     \
      for (int r = 0; r < 16; ++r) {                                        \
        const int rm = (r & 3) + 8 * (r >> 2) + 4 * hi;                     \
        p[r] = exp2a((rm > q5) ? S[r] + NEGS2 : S[r]);                      \
      }                                                                     \
    } else {                                                                \
      _Pragma("unroll")                                                     \
      for (int r = 0; r < 16; ++r) p[r] = exp2a(S[r]);                      \
    }                                                                       \
    lsq += ((p[0] + p[1]) + (p[2] + p[3])) + ((p[4] + p[5]) + (p[6] + p[7]))  \
         + ((p[8] + p[9]) + (p[10] + p[11])) + ((p[12] + p[13]) + (p[14] + p[15])); \
    const bf16x8 pf0 = pack_frag(p[0], p[1], p[2],  p[3],  p[4],  p[5],  p[6],  p[7]);  \
    const bf16x8 pf1 = pack_frag(p[8], p[9], p[10], p[11], p[12], p[13], p[14], p[15]); \
    __builtin_amdgcn_s_setprio(1);                                          \
    acc0 = MFMA32(VC0, pf0, acc0);                                          \
    acc0 = MFMA32(VC1, pf1, acc0);                                          \
    acc1 = MFMA32(VC2, pf0, acc1);                                          \
    acc1 = MFMA32(VC3, pf1, acc1);                                          \
    __builtin_amdgcn_s_setprio(0);                                          \
  } while (0)

  LOADK(kA0, kA1, kA2, kA3, j0);
  KMLD(sA, j0);
  LOADV(vA0, vA1, vA2, vA3, j0);
  QKP(sA, kA0, kA1, kA2, kA3);
  if (j1 - j0 == 1) {
    CONSUME_T(sA, (j1 == T), vA0, vA1, vA2, vA3);
  } else {
    LOADK(kB0, kB1, kB2, kB3, j0 + 1);
    KMLD(sB, j0 + 1);
    int j = j0;
    for (;;) {
      QKP(sB, kB0, kB1, kB2, kB3);                       // scores(j+1)
      CONSUME_P(sA, j, kA0, kA1, kA2, kA3,               // K/km pf -> A
                vB0, vB1, vB2, vB3,                      // V(j+1) -> vB
                vA0, vA1, vA2, vA3);                     // PV with vA
      ++j;
      if (j + 1 >= j1) { CONSUME_T(sB, (j1 == T), vB0, vB1, vB2, vB3); break; }
      QKP(sA, kA0, kA1, kA2, kA3);
      CONSUME_P(sB, j, kB0, kB1, kB2, kB3,
                vA0, vA1, vA2, vA3,
                vB0, vB1, vB2, vB3);
      ++j;
      if (j + 1 >= j1) { CONSUME_T(sA, (j1 == T), vA0, vA1, vA2, vA3); break; }
    }
  }
#undef LOADK
#undef LOADV
#undef KMLD
#undef QKP
#undef CONSUME_P
#undef CONSUME_T
}

// ---------------------------------------------------------------------------
// Kernel 2: fused split-kv attention + LN + FFN + LN.
// grid = Z*32 x 128 (2 waves). Block tp owns q-tiles t1=tp, t2=63-tp.
// ph=0: wave0 [t1, 0..h1) -> dump; wave1 [t2, h2..T2) -> dump
// ph=1: wave0 [t2, 0..h2) -> keep; wave1 [t1, h1..T1) -> keep
// Every wave ~33 iterations (tail-free). Merge = plain add (no-max softmax
// partials are shift-free). One __syncthreads. Epilogue per wave on kept tile.
// ---------------------------------------------------------------------------
__global__ __launch_bounds__(128) void fused_kernel(
    const __bf16* __restrict__ Qp, const __bf16* __restrict__ Kp,
    const __bf16* __restrict__ Vp, const float* __restrict__ kpmS,
    const float* __restrict__ x,
    const __bf16* __restrict__ w1p, const __bf16* __restrict__ w2p,
    float* __restrict__ out)
{
  const int bid = (blockIdx.x & 7) * 256 + (blockIdx.x >> 3);  // XCD chunking
  const int b   = bid >> 5;
  const int tp  = bid & 31;
  const int wv  = threadIdx.x >> 6;
  const int l   = threadIdx.x & 63;
  const int q5  = l & 31;
  const int hi  = l >> 5;

  const int t1 = tp, t2 = 63 - tp;

  __shared__ float part[2][64][36];   // [wave][lane][acc0|acc1|ls] (stride 36)

  const __bf16* qB = Qp + (size_t)b * (64 * 2048) + (size_t)l * 8;
  const __bf16* kB = Kp + (size_t)b * (64 * 2048) + (size_t)l * 8;
  const __bf16* vB = Vp + (size_t)b * (64 * 2048) + (size_t)l * 8;
  const float*  kpb = kpmS + b * NCTX;

  f32x16 acc0, acc1;
  float lsq;
  #pragma unroll
  for (int r = 0; r < 16; ++r) { acc0[r] = 0.f; acc1[r] = 0.f; }
  lsq = 0.f;

  #pragma unroll
  for (int ph = 0; ph < 2; ++ph) {
    const int t = (wv ^ ph) ? t2 : t1;
    const int T = t + 1;
    const int h = (T + 1) >> 1;
    const int j0 = wv ? h : 0;
    const int j1 = wv ? T : h;
    attn_phase(qB + (size_t)t * 2048, kB, vB, kpb,
               T, j0, j1, q5, hi, acc0, acc1, lsq);
    if (ph == 0) {
      float* ps = &part[wv][l][0];
      #pragma unroll
      for (int g = 0; g < 4; ++g) {
        f32x4 t0, t1v;
        #pragma unroll
        for (int jj = 0; jj < 4; ++jj) { t0[jj] = acc0[4 * g + jj]; t1v[jj] = acc1[4 * g + jj]; }
        *(f32x4*)(ps + 4 * g)      = t0;
        *(f32x4*)(ps + 16 + 4 * g) = t1v;
      }
      ps[32] = lsq;
      #pragma unroll
      for (int r = 0; r < 16; ++r) { acc0[r] = 0.f; acc1[r] = 0.f; }
      lsq = 0.f;
    }
  }
  const int tB = wv ? t1 : t2;

  __syncthreads();

  // ---- merge partner's partial (plain add: no-max softmax) ----
  {
    const float* po = &part[wv ^ 1][l][0];
    #pragma unroll
    for (int g = 0; g < 4; ++g) {
      const f32x4 t0 = *(const f32x4*)(po + 4 * g);
      const f32x4 t1v = *(const f32x4*)(po + 16 + 4 * g);
      #pragma unroll
      for (int jj = 0; jj < 4; ++jj) { acc0[4 * g + jj] += t0[jj]; acc1[4 * g + jj] += t1v[jj]; }
    }
    lsq += po[32];
  }

  // ---- fused epilogue: LN1 + FFN + LN2 on tile tB ----
  const int n = tB * 32 + q5;
  const float invl = 1.f / redsum32(lsq);
  const float* xrow = x + ((size_t)(b * NCTX + n)) * DH;

  f32x16 z16;
  #pragma unroll
  for (int r = 0; r < 16; ++r) z16[r] = 0.f;

  float y0[16], y1[16];
  float s1 = 0.f, s2 = 0.f;
  #pragma unroll
  for (int g = 0; g < 4; ++g) {
    const f32x4 xv0 = *(const f32x4*)(xrow + 8 * g + 4 * hi);
    const f32x4 xv1 = *(const f32x4*)(xrow + 32 + 8 * g + 4 * hi);
    #pragma unroll
    for (int jj = 0; jj < 4; ++jj) {
      const float a0 = acc0[4 * g + jj] * invl + xv0[jj];
      const float a1 = acc1[4 * g + jj] * invl + xv1[jj];
      y0[4 * g + jj] = a0; y1[4 * g + jj] = a1;
      s1 += a0 + a1; s2 += a0 * a0 + a1 * a1;
    }
  }
  s1 = redsum32(s1);
  s2 = redsum32(s2);
  {
    const float mu   = s1 * (1.f / 64.f);
    const float var  = s2 * (1.f / 64.f) - mu * mu;
    const float rstd = rsqrtf(var + 1e-5f);
    #pragma unroll
    for (int r = 0; r < 16; ++r) {
      y0[r] = (y0[r] - mu) * rstd;
      y1[r] = (y1[r] - mu) * rstd;
    }
  }

  const bf16x8 yb0 = pack_frag(y0[0], y0[1], y0[2],  y0[3],  y0[4],  y0[5],  y0[6],  y0[7]);
  const bf16x8 yb1 = pack_frag(y0[8], y0[9], y0[10], y0[11], y0[12], y0[13], y0[14], y0[15]);
  const bf16x8 yb2 = pack_frag(y1[0], y1[1], y1[2],  y1[3],  y1[4],  y1[5],  y1[6],  y1[7]);
  const bf16x8 yb3 = pack_frag(y1[8], y1[9], y1[10], y1[11], y1[12], y1[13], y1[14], y1[15]);

  const __bf16* wp1 = w1p + (size_t)l * 8;
  f32x16 hc;
  hc = MFMA32(*(const bf16x8*)(wp1),              yb0, z16);
  hc = MFMA32(*(const bf16x8*)(wp1 + 64 * 8),     yb1, hc);
  hc = MFMA32(*(const bf16x8*)(wp1 + 2 * 64 * 8), yb2, hc);
  hc = MFMA32(*(const bf16x8*)(wp1 + 3 * 64 * 8), yb3, hc);
  float hv[16];
  #pragma unroll
  for (int r = 0; r < 16; ++r) hv[r] = fmaxf(hc[r], 0.f);

  const bf16x8 hb0 = pack_frag(hv[0], hv[1], hv[2],  hv[3],  hv[4],  hv[5],  hv[6],  hv[7]);
  const bf16x8 hb1 = pack_frag(hv[8], hv[9], hv[10], hv[11], hv[12], hv[13], hv[14], hv[15]);

  const __bf16* wp2 = w2p + (size_t)l * 8;
  f32x16 f20, f21;
  f20 = MFMA32(*(const bf16x8*)(wp2),              hb0, z16);
  f20 = MFMA32(*(const bf16x8*)(wp2 + 64 * 8),     hb1, f20);
  f21 = MFMA32(*(const bf16x8*)(wp2 + 2 * 64 * 8), hb0, z16);
  f21 = MFMA32(*(const bf16x8*)(wp2 + 3 * 64 * 8), hb1, f21);

  float v1 = 0.f, v2 = 0.f;
  float va0[16], va1[16];
  #pragma unroll
  for (int r = 0; r < 16; ++r) {
    va0[r] = f20[r] + y0[r];
    va1[r] = f21[r] + y1[r];
    v1 += va0[r] + va1[r];
    v2 += va0[r] * va0[r] + va1[r] * va1[r];
  }
  v1 = redsum32(v1);
  v2 = redsum32(v2);
  const float mu2   = v1 * (1.f / 64.f);
  const float var2  = v2 * (1.f / 64.f) - mu2 * mu2;
  const float rstd2 = rsqrtf(var2 + 1e-5f);

  float* op = out + ((size_t)(b * NCTX + n)) * DH + 4 * hi;
  #pragma unroll
  for (int g = 0; g < 4; ++g) {
    f32x4 st0, st1;
    #pragma unroll
    for (int jj = 0; jj < 4; ++jj) {
      st0[jj] = (va0[4 * g + jj] - mu2) * rstd2;
      st1[jj] = (va1[4 * g + jj] - mu2) * rstd2;
    }
    *(f32x4*)(op + 8 * g)      = st0;
    *(f32x4*)(op + 32 + 8 * g) = st1;
  }
}

// ---------------------------------------------------------------------------
extern "C" void kernel_launch(void* const* d_in, const int* in_sizes, int n_in,
                              void* d_out, int out_size, void* d_ws, size_t ws_size,
                              hipStream_t stream)
{
  const float* x   = (const float*)d_in[0];
  const float* wq  = (const float*)d_in[1];
  const float* wk  = (const float*)d_in[2];
  const float* wv  = (const float*)d_in[3];
  const float* w1  = (const float*)d_in[4];
  const float* w2  = (const float*)d_in[5];
  const float* kpm = (const float*)d_in[6];
  // d_in[7] = causal_mask: handled structurally (triu(k=1) == -1e9 additive)
  float* out = (float*)d_out;

  char* ws = (char*)d_ws;
  const size_t nelem = (size_t)ZB * NCTX * DH;     // 8388608
  __bf16* Qp   = (__bf16*)(ws);
  __bf16* Kp   = (__bf16*)(ws + nelem * 2);
  __bf16* Vp   = (__bf16*)(ws + nelem * 4);
  float*  kpmS = (float*)(ws + nelem * 6);         // ZB*NCTX f32
  __bf16* w1p  = (__bf16*)(ws + nelem * 6 + (size_t)ZB * NCTX * 4);
  __bf16* w2p  = w1p + 4 * 64 * 8;

  proj_kernel <<<1024, 256, 0, stream>>>(x, wq, wk, wv, w1, w2, kpm,
                                         Qp, Kp, Vp, kpmS, w1p, w2p);
  fused_kernel<<<ZB * 32, 128, 0, stream>>>(Qp, Kp, Vp, kpmS, x, w1p, w2p, out);
}

// Round 16
// 97.083 us; speedup vs baseline: 2.3013x; 1.0006x over previous
//
#include <hip/hip_runtime.h>
#include <cstdint>
#include <cstddef>

// Fused transformer block: out = LN(FFN(LN(attn(x)+x)) + LN(attn(x)+x))
// Z=64, N_CTX=2048, D=64, DFF=32, causal, single head.
// proj: QKV via MFMA -> fragment-packed Qp/Kp/Vp (R10: coalesced 16B/lane).
// fused: split-kv flash attention, no-max base-2 softmax, additive merge.
// R11/13: kpm as QK C-init; 2-deep K/km/V register pipeline.
// R15-revert: R14/15's LDS-staged epilogue failed correctness twice with a
// stride-independent bug (identical absmax at stride 65 and 68) -> abandoned;
// this is the proven R13 kernel (97.1 us, absmax 0.031).

#define ZB   64
#define NCTX 2048
#define DH   64
#define DFF  32
// base-2 softmax: score*SM_SCALE*log2(e); mask -1e9 pre-scale -> NEGS2 in log2 domain
#define SC2   0.18033688011112042f
#define NEGS2 (-1.8033688e8f)

typedef float f32x4  __attribute__((ext_vector_type(4)));
typedef float f32x16 __attribute__((ext_vector_type(16)));
typedef __bf16 bf16x8 __attribute__((ext_vector_type(8)));
typedef unsigned int u32x4 __attribute__((ext_vector_type(4)));

#define MFMA32(a, b, c) __builtin_amdgcn_mfma_f32_32x32x16_bf16((a), (b), (c), 0, 0, 0)

static __device__ __forceinline__ unsigned cvtpk_bf16(float a, float b) {
  unsigned r;
  asm("v_cvt_pk_bf16_f32 %0, %1, %2" : "=v"(r) : "v"(a), "v"(b));
  return r;
}
static __device__ __forceinline__ void plswap32(unsigned &a, unsigned &b) {
  asm volatile("v_permlane32_swap_b32 %0, %1" : "+v"(a), "+v"(b));
}
static __device__ __forceinline__ float exp2a(float x) {
  float r;
  asm("v_exp_f32 %0, %1" : "=v"(r) : "v"(x));
  return r;
}
static __device__ __forceinline__ float redsum32(float v) {
  return v + __shfl_xor(v, 32);   // lane^32; proven-correct path
}
// build a bf16x8 frag ordered {own-half, partner-half} from 8 f32 regs whose
// local row is rm = (r&3) + 8*(r>>2) + 4*hi (the 32x32 C-layout pattern)
static __device__ __forceinline__ bf16x8 pack_frag(
    float v0, float v1, float v2, float v3,
    float v4, float v5, float v6, float v7) {
  unsigned A0 = cvtpk_bf16(v0, v1), A1 = cvtpk_bf16(v2, v3);
  unsigned B0 = cvtpk_bf16(v4, v5), B1 = cvtpk_bf16(v6, v7);
  plswap32(A0, B0); plswap32(A1, B1);
  u32x4 u = {A0, A1, B0, B1};
  return __builtin_bit_cast(bf16x8, u);
}

// ---------------------------------------------------------------------------
// Kernel 1: QKV projection via MFMA (grid 1024 x 256, wave = 32-token tile).
// Outputs in fragment-packed order (frag stride 512 elem, tile stride 2048):
//   Qp/Kp[b][tk][c][l][8]: lane l=(q5,hi') frag c holds Q[tok q5][16c+8hi'+i]
//   Vp[b][tk][f][l][8]: f=(db,kvh); lane l=(d5,hi) holds V[16kvh+8hi+i][d5+32db]
// Q pre-scaled by SC2; kpmS = kpm*SC2; block 0 wave 0 packs w1p/w2p.
// ---------------------------------------------------------------------------
__global__ __launch_bounds__(256) void proj_kernel(
    const float* __restrict__ x, const float* __restrict__ wq,
    const float* __restrict__ wk, const float* __restrict__ wv,
    const float* __restrict__ w1, const float* __restrict__ w2,
    const float* __restrict__ kpm,
    __bf16* __restrict__ Qp, __bf16* __restrict__ Kp, __bf16* __restrict__ Vp,
    float* __restrict__ kpmS, __bf16* __restrict__ w1p, __bf16* __restrict__ w2p)
{
  const int wid = threadIdx.x >> 6;
  const int l   = threadIdx.x & 63;
  const int q5  = l & 31, hi = l >> 5;
  const int tile = blockIdx.x * 4 + wid;        // 4096 tiles of 32 tokens
  const int b   = tile >> 6;                    // 64 tiles per batch
  const int tk  = tile & 63;                    // tile index within batch
  const int n   = (tk << 5) + q5;               // this lane's token

  __shared__ float vtile[4][32][67];            // [wave][token][d], 67: bank-clean

  if (blockIdx.x == 0 && wid == 0) {
    #pragma unroll
    for (int kk = 0; kk < 4; ++kk)
      #pragma unroll
      for (int i = 0; i < 8; ++i)
        w1p[(kk * 64 + l) * 8 + i] = (__bf16)w1[(16 * kk + 8 * hi + i) * DFF + q5];
    #pragma unroll
    for (int dt = 0; dt < 2; ++dt)
      #pragma unroll
      for (int kk2 = 0; kk2 < 2; ++kk2)
        #pragma unroll
        for (int i = 0; i < 8; ++i)
          w2p[((dt * 2 + kk2) * 64 + l) * 8 + i] =
              (__bf16)w2[(16 * kk2 + 8 * hi + i) * DH + 32 * dt + q5];
  }
  if (hi == 0) kpmS[b * NCTX + n] = kpm[b * NCTX + n] * SC2;

  const float* xr = x + ((size_t)(b * NCTX + n)) * DH + 8 * hi;
  bf16x8 xb[4];
  #pragma unroll
  for (int kk = 0; kk < 4; ++kk) {
    const f32x4 a = *(const f32x4*)(xr + 16 * kk);
    const f32x4 c = *(const f32x4*)(xr + 16 * kk + 4);
    u32x4 u = {cvtpk_bf16(a[0], a[1]), cvtpk_bf16(a[2], a[3]),
               cvtpk_bf16(c[0], c[1]), cvtpk_bf16(c[2], c[3])};
    xb[kk] = __builtin_bit_cast(bf16x8, u);
  }

  const size_t tbase = ((size_t)(b * 64 + tk)) * 2048;   // packed tile base

  #pragma unroll
  for (int m = 0; m < 3; ++m) {
    const float* w = (m == 0) ? wq : (m == 1) ? wk : wv;

    f32x16 c0, c1;
    #pragma unroll
    for (int r = 0; r < 16; ++r) { c0[r] = 0.f; c1[r] = 0.f; }

    #pragma unroll
    for (int kk = 0; kk < 4; ++kk) {
      const float* wp = w + (size_t)(16 * kk + 8 * hi) * DH + q5;
      float f0[8], f1[8];
      #pragma unroll
      for (int i = 0; i < 8; ++i) { f0[i] = wp[i * DH]; f1[i] = wp[i * DH + 32]; }
      u32x4 ua = {cvtpk_bf16(f0[0], f0[1]), cvtpk_bf16(f0[2], f0[3]),
                  cvtpk_bf16(f0[4], f0[5]), cvtpk_bf16(f0[6], f0[7])};
      u32x4 ub = {cvtpk_bf16(f1[0], f1[1]), cvtpk_bf16(f1[2], f1[3]),
                  cvtpk_bf16(f1[4], f1[5]), cvtpk_bf16(f1[6], f1[7])};
      c0 = MFMA32(__builtin_bit_cast(bf16x8, ua), xb[kk], c0);
      c1 = MFMA32(__builtin_bit_cast(bf16x8, ub), xb[kk], c1);
    }

    if (m == 0) {
      #pragma unroll
      for (int r = 0; r < 16; ++r) { c0[r] *= SC2; c1[r] *= SC2; }
    }

    if (m < 2) {
      // frag c = 2hi + (g>>1), slot = (g&1)*32 + q5 (verified R10)
      __bf16* dst = ((m == 0) ? Qp : Kp) + tbase;
      #pragma unroll
      for (int g = 0; g < 4; ++g) {
        unsigned A0 = cvtpk_bf16(c0[4 * g],     c0[4 * g + 1]);
        unsigned A1 = cvtpk_bf16(c0[4 * g + 2], c0[4 * g + 3]);
        unsigned B0 = cvtpk_bf16(c1[4 * g],     c1[4 * g + 1]);
        unsigned B1 = cvtpk_bf16(c1[4 * g + 2], c1[4 * g + 3]);
        plswap32(A0, B0); plswap32(A1, B1);
        u32x4 u = {A0, A1, B0, B1};
        const int c    = 2 * hi + (g >> 1);
        const int slot = ((g & 1) << 5) + q5;
        *(u32x4*)(dst + ((size_t)c * 64 + slot) * 8) = u;
      }
    } else {
      // V: stage f32 tile in LDS (wave-private), emit packed A-frag stores
      #pragma unroll
      for (int r = 0; r < 16; ++r) {
        const int d = (r & 3) + 8 * (r >> 2) + 4 * hi;
        vtile[wid][q5][d]      = c0[r];
        vtile[wid][q5][d + 32] = c1[r];
      }
      asm volatile("s_waitcnt lgkmcnt(0)" ::: "memory");
      __builtin_amdgcn_sched_barrier(0);
      __bf16* vdst = Vp + tbase + (size_t)l * 8;
      #pragma unroll
      for (int f = 0; f < 4; ++f) {
        const int krow = 16 * (f & 1) + 8 * hi;     // kv row in tile
        const int dcol = q5 + 32 * (f >> 1);        // d column
        u32x4 u;
        #pragma unroll
        for (int ii = 0; ii < 4; ++ii)
          u[ii] = cvtpk_bf16(vtile[wid][krow + 2 * ii][dcol],
                             vtile[wid][krow + 2 * ii + 1][dcol]);
        *(u32x4*)(vdst + (size_t)f * 512) = u;
      }
    }
  }
}

// ---------------------------------------------------------------------------
// attn phase: q-tile t, kv tiles [j0, j1), fully 2-deep pipelined (K, km, V).
// Loop-top invariant: sX = scores(j) ready; kY = K(j+1); sY = km(j+1);
// vX = V(j). Body: QK(j+1) -> consume(j): issue V(j+1)->vY, exp (frees sX),
// prefetch K(j+2)->kX + km(j+2)->sX, sum, pack, PV with vX. Diag mask only
// in the tail consume. km rides in the score buffer as the MFMA C-init.
// ---------------------------------------------------------------------------
static __device__ __forceinline__ void attn_phase(
    const __bf16* __restrict__ qt,     // Qp batch base + t*2048 + l*8
    const __bf16* __restrict__ kBp,    // Kp batch base + l*8
    const __bf16* __restrict__ vBp,    // Vp batch base + l*8
    const float*  __restrict__ kpb,    // kpmS + b*NCTX
    int T, int j0, int j1, int q5, int hi,
    f32x16& acc0, f32x16& acc1, float& lsq)
{
  if (j0 >= j1) return;

  const bf16x8 qf0 = *(const bf16x8*)(qt);
  const bf16x8 qf1 = *(const bf16x8*)(qt + 512);
  const bf16x8 qf2 = *(const bf16x8*)(qt + 1024);
  const bf16x8 qf3 = *(const bf16x8*)(qt + 1536);

  bf16x8 kA0, kA1, kA2, kA3, kB0, kB1, kB2, kB3;
  bf16x8 vA0, vA1, vA2, vA3, vB0, vB1, vB2, vB3;
  f32x16 sA, sB;

#define LOADK(P0, P1, P2, P3, J) do {                                       \
    const __bf16* _kp = kBp + (size_t)(J) * 2048;                           \
    P0 = *(const bf16x8*)(_kp);        P1 = *(const bf16x8*)(_kp + 512);    \
    P2 = *(const bf16x8*)(_kp + 1024); P3 = *(const bf16x8*)(_kp + 1536);   \
  } while (0)

#define LOADV(P0, P1, P2, P3, J) do {                                       \
    const __bf16* _vp = vBp + (size_t)(J) * 2048;                           \
    P0 = *(const bf16x8*)(_vp);        P1 = *(const bf16x8*)(_vp + 512);    \
    P2 = *(const bf16x8*)(_vp + 1024); P3 = *(const bf16x8*)(_vp + 1536);   \
  } while (0)

#define KMLD(S, J) do {                                                     \
    const float* _mp = kpb + (J) * 32 + 4 * hi;                             \
    const f32x4 _m0 = *(const f32x4*)(_mp);                                 \
    const f32x4 _m1 = *(const f32x4*)(_mp + 8);                             \
    const f32x4 _m2 = *(const f32x4*)(_mp + 16);                            \
    const f32x4 _m3 = *(const f32x4*)(_mp + 24);                            \
    _Pragma("unroll")                                                       \
    for (int _jj = 0; _jj < 4; ++_jj) {                                     \
      S[_jj] = _m0[_jj];      S[4 + _jj] = _m1[_jj];                        \
      S[8 + _jj] = _m2[_jj];  S[12 + _jj] = _m3[_jj];                       \
    }                                                                       \
  } while (0)

#define QKP(S, P0, P1, P2, P3) do {                                         \
    __builtin_amdgcn_s_setprio(1);                                          \
    S = MFMA32(P0, qf0, S);                                                 \
    S = MFMA32(P1, qf1, S);                                                 \
    S = MFMA32(P2, qf2, S);                                                 \
    S = MFMA32(P3, qf3, S);                                                 \
    __builtin_amdgcn_s_setprio(0);                                          \
  } while (0)

// pipelined consume of scores S for tile J (never diagonal): issue V(J+1)
// into VN*, exp, prefetch K(clamp(J+2))->PK* and km->S, sum, pack, PV w/ VC*.
#define CONSUME_P(S, J, PK0, PK1, PK2, PK3, VN0, VN1, VN2, VN3,             \
                  VC0, VC1, VC2, VC3) do {                                  \
    LOADV(VN0, VN1, VN2, VN3, (J) + 1);                                     \
    float p[16];                                                            \
    _Pragma("unroll")                                                       \
    for (int r = 0; r < 16; ++r) p[r] = exp2a(S[r]);                        \
    {                                                                       \
      const int _jn = ((J) + 2 < j1) ? (J) + 2 : j1 - 1;                    \
      LOADK(PK0, PK1, PK2, PK3, _jn);                                       \
      KMLD(S, _jn);                                                         \
    }                                                                       \
    lsq += ((p[0] + p[1]) + (p[2] + p[3])) + ((p[4] + p[5]) + (p[6] + p[7]))  \
         + ((p[8] + p[9]) + (p[10] + p[11])) + ((p[12] + p[13]) + (p[14] + p[15])); \
    const bf16x8 pf0 = pack_frag(p[0], p[1], p[2],  p[3],  p[4],  p[5],  p[6],  p[7]);  \
    const bf16x8 pf1 = pack_frag(p[8], p[9], p[10], p[11], p[12], p[13], p[14], p[15]); \
    __builtin_amdgcn_s_setprio(1);                                          \
    acc0 = MFMA32(VC0, pf0, acc0);                                          \
    acc0 = MFMA32(VC1, pf1, acc0);                                          \
    acc1 = MFMA32(VC2, pf0, acc1);                                          \
    acc1 = MFMA32(VC3, pf1, acc1);                                          \
    __builtin_amdgcn_s_setprio(0);                                          \
  } while (0)

// tail consume (no prefetch; optional diagonal mask), PV with VC*.
#define CONSUME_T(S, DG, VC0, VC1, VC2, VC3) do {                           \
    float p[16];                                                            \
    if (DG) {                                                               \
      _Pragma("unroll")                                                     \
      for (int r = 0; r < 16; ++r) {                                        \
        const int rm = (r & 3) + 8 * (r >> 2) + 4 * hi;                     \
        p[r] = exp2a((rm > q5) ? S[r] + NEGS2 : S[r]);                      \
      }                                                                     \
    } else {                                                                \
      _Pragma("unroll")                                                     \
      for (int r = 0; r < 16; ++r) p[r] = exp2a(S[r]);                      \
    }                                                                       \
    lsq += ((p[0] + p[1]) + (p[2] + p[3])) + ((p[4] + p[5]) + (p[6] + p[7]))  \
         + ((p[8] + p[9]) + (p[10] + p[11])) + ((p[12] + p[13]) + (p[14] + p[15])); \
    const bf16x8 pf0 = pack_frag(p[0], p[1], p[2],  p[3],  p[4],  p[5],  p[6],  p[7]);  \
    const bf16x8 pf1 = pack_frag(p[8], p[9], p[10], p[11], p[12], p[13], p[14], p[15]); \
    __builtin_amdgcn_s_setprio(1);                                          \
    acc0 = MFMA32(VC0, pf0, acc0);                                          \
    acc0 = MFMA32(VC1, pf1, acc0);                                          \
    acc1 = MFMA32(VC2, pf0, acc1);                                          \
    acc1 = MFMA32(VC3, pf1, acc1);                                          \
    __builtin_amdgcn_s_setprio(0);                                          \
  } while (0)

  LOADK(kA0, kA1, kA2, kA3, j0);
  KMLD(sA, j0);
  LOADV(vA0, vA1, vA2, vA3, j0);
  QKP(sA, kA0, kA1, kA2, kA3);
  if (j1 - j0 == 1) {
    CONSUME_T(sA, (j1 == T), vA0, vA1, vA2, vA3);
  } else {
    LOADK(kB0, kB1, kB2, kB3, j0 + 1);
    KMLD(sB, j0 + 1);
    int j = j0;
    for (;;) {
      QKP(sB, kB0, kB1, kB2, kB3);                       // scores(j+1)
      CONSUME_P(sA, j, kA0, kA1, kA2, kA3,               // K/km pf -> A
                vB0, vB1, vB2, vB3,                      // V(j+1) -> vB
                vA0, vA1, vA2, vA3);                     // PV with vA
      ++j;
      if (j + 1 >= j1) { CONSUME_T(sB, (j1 == T), vB0, vB1, vB2, vB3); break; }
      QKP(sA, kA0, kA1, kA2, kA3);
      CONSUME_P(sB, j, kB0, kB1, kB2, kB3,
                vA0, vA1, vA2, vA3,
                vB0, vB1, vB2, vB3);
      ++j;
      if (j + 1 >= j1) { CONSUME_T(sA, (j1 == T), vA0, vA1, vA2, vA3); break; }
    }
  }
#undef LOADK
#undef LOADV
#undef KMLD
#undef QKP
#undef CONSUME_P
#undef CONSUME_T
}

// ---------------------------------------------------------------------------
// Kernel 2: fused split-kv attention + LN + FFN + LN.
// grid = Z*32 x 128 (2 waves). Block tp owns q-tiles t1=tp, t2=63-tp.
// ph=0: wave0 [t1, 0..h1) -> dump; wave1 [t2, h2..T2) -> dump
// ph=1: wave0 [t2, 0..h2) -> keep; wave1 [t1, h1..T1) -> keep
// Every wave ~33 iterations (tail-free). Merge = plain add (no-max softmax
// partials are shift-free). One __syncthreads. Epilogue per wave on kept tile.
// ---------------------------------------------------------------------------
__global__ __launch_bounds__(128) void fused_kernel(
    const __bf16* __restrict__ Qp, const __bf16* __restrict__ Kp,
    const __bf16* __restrict__ Vp, const float* __restrict__ kpmS,
    const float* __restrict__ x,
    const __bf16* __restrict__ w1p, const __bf16* __restrict__ w2p,
    float* __restrict__ out)
{
  const int bid = (blockIdx.x & 7) * 256 + (blockIdx.x >> 3);  // XCD chunking
  const int b   = bid >> 5;
  const int tp  = bid & 31;
  const int wv  = threadIdx.x >> 6;
  const int l   = threadIdx.x & 63;
  const int q5  = l & 31;
  const int hi  = l >> 5;

  const int t1 = tp, t2 = 63 - tp;

  __shared__ float part[2][64][36];   // [wave][lane][acc0|acc1|ls] (stride 36)

  const __bf16* qB = Qp + (size_t)b * (64 * 2048) + (size_t)l * 8;
  const __bf16* kB = Kp + (size_t)b * (64 * 2048) + (size_t)l * 8;
  const __bf16* vB = Vp + (size_t)b * (64 * 2048) + (size_t)l * 8;
  const float*  kpb = kpmS + b * NCTX;

  f32x16 acc0, acc1;
  float lsq;
  #pragma unroll
  for (int r = 0; r < 16; ++r) { acc0[r] = 0.f; acc1[r] = 0.f; }
  lsq = 0.f;

  #pragma unroll
  for (int ph = 0; ph < 2; ++ph) {
    const int t = (wv ^ ph) ? t2 : t1;
    const int T = t + 1;
    const int h = (T + 1) >> 1;
    const int j0 = wv ? h : 0;
    const int j1 = wv ? T : h;
    attn_phase(qB + (size_t)t * 2048, kB, vB, kpb,
               T, j0, j1, q5, hi, acc0, acc1, lsq);
    if (ph == 0) {
      float* ps = &part[wv][l][0];
      #pragma unroll
      for (int g = 0; g < 4; ++g) {
        f32x4 t0, t1v;
        #pragma unroll
        for (int jj = 0; jj < 4; ++jj) { t0[jj] = acc0[4 * g + jj]; t1v[jj] = acc1[4 * g + jj]; }
        *(f32x4*)(ps + 4 * g)      = t0;
        *(f32x4*)(ps + 16 + 4 * g) = t1v;
      }
      ps[32] = lsq;
      #pragma unroll
      for (int r = 0; r < 16; ++r) { acc0[r] = 0.f; acc1[r] = 0.f; }
      lsq = 0.f;
    }
  }
  const int tB = wv ? t1 : t2;

  __syncthreads();

  // ---- merge partner's partial (plain add: no-max softmax) ----
  {
    const float* po = &part[wv ^ 1][l][0];
    #pragma unroll
    for (int g = 0; g < 4; ++g) {
      const f32x4 t0 = *(const f32x4*)(po + 4 * g);
      const f32x4 t1v = *(const f32x4*)(po + 16 + 4 * g);
      #pragma unroll
      for (int jj = 0; jj < 4; ++jj) { acc0[4 * g + jj] += t0[jj]; acc1[4 * g + jj] += t1v[jj]; }
    }
    lsq += po[32];
  }

  // ---- fused epilogue: LN1 + FFN + LN2 on tile tB ----
  const int n = tB * 32 + q5;
  const float invl = 1.f / redsum32(lsq);
  const float* xrow = x + ((size_t)(b * NCTX + n)) * DH;

  f32x16 z16;
  #pragma unroll
  for (int r = 0; r < 16; ++r) z16[r] = 0.f;

  float y0[16], y1[16];
  float s1 = 0.f, s2 = 0.f;
  #pragma unroll
  for (int g = 0; g < 4; ++g) {
    const f32x4 xv0 = *(const f32x4*)(xrow + 8 * g + 4 * hi);
    const f32x4 xv1 = *(const f32x4*)(xrow + 32 + 8 * g + 4 * hi);
    #pragma unroll
    for (int jj = 0; jj < 4; ++jj) {
      const float a0 = acc0[4 * g + jj] * invl + xv0[jj];
      const float a1 = acc1[4 * g + jj] * invl + xv1[jj];
      y0[4 * g + jj] = a0; y1[4 * g + jj] = a1;
      s1 += a0 + a1; s2 += a0 * a0 + a1 * a1;
    }
  }
  s1 = redsum32(s1);
  s2 = redsum32(s2);
  {
    const float mu   = s1 * (1.f / 64.f);
    const float var  = s2 * (1.f / 64.f) - mu * mu;
    const float rstd = rsqrtf(var + 1e-5f);
    #pragma unroll
    for (int r = 0; r < 16; ++r) {
      y0[r] = (y0[r] - mu) * rstd;
      y1[r] = (y1[r] - mu) * rstd;
    }
  }

  const bf16x8 yb0 = pack_frag(y0[0], y0[1], y0[2],  y0[3],  y0[4],  y0[5],  y0[6],  y0[7]);
  const bf16x8 yb1 = pack_frag(y0[8], y0[9], y0[10], y0[11], y0[12], y0[13], y0[14], y0[15]);
  const bf16x8 yb2 = pack_frag(y1[0], y1[1], y1[2],  y1[3],  y1[4],  y1[5],  y1[6],  y1[7]);
  const bf16x8 yb3 = pack_frag(y1[8], y1[9], y1[10], y1[11], y1[12], y1[13], y1[14], y1[15]);

  const __bf16* wp1 = w1p + (size_t)l * 8;
  f32x16 hc;
  hc = MFMA32(*(const bf16x8*)(wp1),              yb0, z16);
  hc = MFMA32(*(const bf16x8*)(wp1 + 64 * 8),     yb1, hc);
  hc = MFMA32(*(const bf16x8*)(wp1 + 2 * 64 * 8), yb2, hc);
  hc = MFMA32(*(const bf16x8*)(wp1 + 3 * 64 * 8), yb3, hc);
  float hv[16];
  #pragma unroll
  for (int r = 0; r < 16; ++r) hv[r] = fmaxf(hc[r], 0.f);

  const bf16x8 hb0 = pack_frag(hv[0], hv[1], hv[2],  hv[3],  hv[4],  hv[5],  hv[6],  hv[7]);
  const bf16x8 hb1 = pack_frag(hv[8], hv[9], hv[10], hv[11], hv[12], hv[13], hv[14], hv[15]);

  const __bf16* wp2 = w2p + (size_t)l * 8;
  f32x16 f20, f21;
  f20 = MFMA32(*(const bf16x8*)(wp2),              hb0, z16);
  f20 = MFMA32(*(const bf16x8*)(wp2 + 64 * 8),     hb1, f20);
  f21 = MFMA32(*(const bf16x8*)(wp2 + 2 * 64 * 8), hb0, z16);
  f21 = MFMA32(*(const bf16x8*)(wp2 + 3 * 64 * 8), hb1, f21);

  float v1 = 0.f, v2 = 0.f;
  float va0[16], va1[16];
  #pragma unroll
  for (int r = 0; r < 16; ++r) {
    va0[r] = f20[r] + y0[r];
    va1[r] = f21[r] + y1[r];
    v1 += va0[r] + va1[r];
    v2 += va0[r] * va0[r] + va1[r] * va1[r];
  }
  v1 = redsum32(v1);
  v2 = redsum32(v2);
  const float mu2   = v1 * (1.f / 64.f);
  const float var2  = v2 * (1.f / 64.f) - mu2 * mu2;
  const float rstd2 = rsqrtf(var2 + 1e-5f);

  float* op = out + ((size_t)(b * NCTX + n)) * DH + 4 * hi;
  #pragma unroll
  for (int g = 0; g < 4; ++g) {
    f32x4 st0, st1;
    #pragma unroll
    for (int jj = 0; jj < 4; ++jj) {
      st0[jj] = (va0[4 * g + jj] - mu2) * rstd2;
      st1[jj] = (va1[4 * g + jj] - mu2) * rstd2;
    }
    *(f32x4*)(op + 8 * g)      = st0;
    *(f32x4*)(op + 32 + 8 * g) = st1;
  }
}

// ---------------------------------------------------------------------------
extern "C" void kernel_launch(void* const* d_in, const int* in_sizes, int n_in,
                              void* d_out, int out_size, void* d_ws, size_t ws_size,
                              hipStream_t stream)
{
  const float* x   = (const float*)d_in[0];
  const float* wq  = (const float*)d_in[1];
  const float* wk  = (const float*)d_in[2];
  const float* wv  = (const float*)d_in[3];
  const float* w1  = (const float*)d_in[4];
  const float* w2  = (const float*)d_in[5];
  const float* kpm = (const float*)d_in[6];
  // d_in[7] = causal_mask: handled structurally (triu(k=1) == -1e9 additive)
  float* out = (float*)d_out;

  char* ws = (char*)d_ws;
  const size_t nelem = (size_t)ZB * NCTX * DH;     // 8388608
  __bf16* Qp   = (__bf16*)(ws);
  __bf16* Kp   = (__bf16*)(ws + nelem * 2);
  __bf16* Vp   = (__bf16*)(ws + nelem * 4);
  float*  kpmS = (float*)(ws + nelem * 6);         // ZB*NCTX f32
  __bf16* w1p  = (__bf16*)(ws + nelem * 6 + (size_t)ZB * NCTX * 4);
  __bf16* w2p  = w1p + 4 * 64 * 8;

  proj_kernel <<<1024, 256, 0, stream>>>(x, wq, wk, wv, w1, w2, kpm,
                                         Qp, Kp, Vp, kpmS, w1p, w2p);
  fused_kernel<<<ZB * 32, 128, 0, stream>>>(Qp, Kp, Vp, kpmS, x, w1p, w2p, out);
}